// Round 8
// baseline (336.452 us; speedup 1.0000x reference)
//
#include <hip/hip_runtime.h>
#include <math.h>

#define TOK 1568      // B*N = 8*196
#define MPAD 1664     // 13 * 128
#define DIM 768
#define HN 12
#define SEQ 196
#define YD 64
#define MXI 3072
#define BETA_F 0.125f
#define INV_BETA 8.0f
#define LN_EPS_F 1e-5f

// P/PT padded geometry: rows 208 (13*16), cols 224 (7*32)
#define PROWS 208
#define PCOLS 224
#define PAREA (PROWS * PCOLS)

// energy partials (doubles): attn ver*96+bh, ver 0..4 -> [0,480)
// hop base [480,792) ; hop trial t*312 -> [792,2040)
#define EP_HOPB 480
#define EP_HOPT 792
#define EP_TOTAL 2040

typedef __bf16 v8bf __attribute__((ext_vector_type(8)));
typedef __bf16 v4bf __attribute__((ext_vector_type(4)));
typedef float  v4f  __attribute__((ext_vector_type(4)));

__device__ __forceinline__ v8bf zero8() {
  v8bf v = { (__bf16)0.f, (__bf16)0.f, (__bf16)0.f, (__bf16)0.f,
             (__bf16)0.f, (__bf16)0.f, (__bf16)0.f, (__bf16)0.f };
  return v;
}

// ------------------------------------------------------------------
// Stage one 128x32 bf16 tile into LDS (global_load_lds width=16),
// 16B-chunk XOR swizzle (neutral for conflicts, kept from R7 - verified).
// ------------------------------------------------------------------
__device__ __forceinline__ void stage_tile(
    const __bf16* __restrict__ G, int ldK, int r0, int k0,
    __bf16* S, int tid, int w)
{
#pragma unroll
  for (int r = 0; r < 2; r++) {
    int ch = (r << 8) + tid;
    int row = ch >> 2;
    int col = (ch & 3) ^ ((row >> 1) & 3);
    __builtin_amdgcn_global_load_lds(
        (__attribute__((address_space(1))) uint32_t*)(G + (size_t)(r0 + row) * ldK + k0 + (col << 3)),
        (__attribute__((address_space(3))) uint32_t*)(S + (r << 11) + (w << 9)),
        16, 0, 0);
  }
}

// ------------------------------------------------------------------
// bf16 MFMA GEMM core: acc += A[m0:+128, kbase:+nk*32] @ B[n0:+128, ...]^T
// smem: As 2x4096 bf16 | Bs 2x4096 bf16 (32768 B)
// ------------------------------------------------------------------
__device__ __forceinline__ void gemm_core_bf16(
    char* smem, const __bf16* __restrict__ A, int ldA,
    const __bf16* __restrict__ B, int ldB,
    int m0, int n0, int kbase, int nk, v4f acc[4][4], int tid)
{
  __bf16* As = (__bf16*)smem;
  __bf16* Bs = (__bf16*)smem + 8192;
  int lane = tid & 63, w = tid >> 6;
  int wm = (w & 1) << 6, wn = (w >> 1) << 6;
  stage_tile(A, ldA, m0, kbase, As, tid, w);
  stage_tile(B, ldB, n0, kbase, Bs, tid, w);
  for (int kt = 0; kt < nk; kt++) {
    __syncthreads();
    int nxt = kt + 1;
    if (nxt < nk) {
      stage_tile(A, ldA, m0, kbase + (nxt << 5), As + ((nxt & 1) << 12), tid, w);
      stage_tile(B, ldB, n0, kbase + (nxt << 5), Bs + ((nxt & 1) << 12), tid, w);
    }
    const __bf16* Ac = As + ((kt & 1) << 12);
    const __bf16* Bc = Bs + ((kt & 1) << 12);
    int mrow = lane & 15, q = lane >> 4;
    v8bf af[4], bfr[4];
#pragma unroll
    for (int i = 0; i < 4; i++) {
      int rA = wm + (i << 4) + mrow;
      int rB = wn + (i << 4) + mrow;
      af[i]  = *(const v8bf*)(Ac + rA * 32 + ((q ^ ((rA >> 1) & 3)) << 3));
      bfr[i] = *(const v8bf*)(Bc + rB * 32 + ((q ^ ((rB >> 1) & 3)) << 3));
    }
#pragma unroll
    for (int i = 0; i < 4; i++)
#pragma unroll
      for (int j = 0; j < 4; j++)
        acc[i][j] = __builtin_amdgcn_mfma_f32_16x16x32_bf16(af[i], bfr[j], acc[i][j], 0, 0, 0);
  }
}

__device__ __forceinline__ void acc_zero(v4f acc[4][4]) {
  v4f z = {0.f, 0.f, 0.f, 0.f};
#pragma unroll
  for (int i = 0; i < 4; i++)
#pragma unroll
    for (int j = 0; j < 4; j++) acc[i][j] = z;
}

// epilogue: store bf16 C [*, N]
__device__ __forceinline__ void epi_store_bf16(
    v4f acc[4][4], __bf16* C, int N, int m0, int n0, int tid)
{
  int lane = tid & 63, w = tid >> 6;
  int wm = (w & 1) << 6, wn = (w >> 1) << 6;
  int quad = lane >> 4, ncol = lane & 15;
#pragma unroll
  for (int i = 0; i < 4; i++)
#pragma unroll
    for (int j = 0; j < 4; j++) {
      int row = m0 + wm + (i << 4) + (quad << 2);
      int col = n0 + wn + (j << 4) + ncol;
#pragma unroll
      for (int r = 0; r < 4; r++)
        C[(size_t)(row + r) * N + col] = (__bf16)acc[i][j][r];
    }
}

// epilogue: store f32 C [*, 768]
__device__ __forceinline__ void epi_store_f32(
    v4f acc[4][4], float* C, int m0, int n0, int tid)
{
  int lane = tid & 63, w = tid >> 6;
  int wm = (w & 1) << 6, wn = (w >> 1) << 6;
  int quad = lane >> 4, ncol = lane & 15;
#pragma unroll
  for (int i = 0; i < 4; i++)
#pragma unroll
    for (int j = 0; j < 4; j++) {
      int row = m0 + wm + (i << 4) + (quad << 2);
      int col = n0 + wn + (j << 4) + ncol;
#pragma unroll
      for (int r = 0; r < 4; r++)
        C[(size_t)(row + r) * DIM + col] = acc[i][j][r];
    }
}

// epilogue: relu -> bf16 store (N cols) + energy partial
__device__ __forceinline__ void epi_relu_energy(
    v4f acc[4][4], __bf16* C, int N, int m0, int n0, int tid,
    double* ered, double* ep_slot)
{
  int lane = tid & 63, w = tid >> 6;
  int wm = (w & 1) << 6, wn = (w >> 1) << 6;
  int quad = lane >> 4, ncol = lane & 15;
  float e = 0.f;
#pragma unroll
  for (int i = 0; i < 4; i++)
#pragma unroll
    for (int j = 0; j < 4; j++) {
      int row = m0 + wm + (i << 4) + (quad << 2);
      int col = n0 + wn + (j << 4) + ncol;
#pragma unroll
      for (int r = 0; r < 4; r++) {
        float v = acc[i][j][r];
        v = v > 0.f ? v : 0.f;
        e += v * v;
        C[(size_t)(row + r) * N + col] = (__bf16)v;
      }
    }
  for (int o = 32; o; o >>= 1) e += __shfl_xor(e, o, 64);
  if (lane == 0) ered[w] = (double)e;
  __syncthreads();
  if (tid == 0)
    *ep_slot = -0.5 * ((ered[0] + ered[1]) + (ered[2] + ered[3]));
}

// ------------------------------------------------------------------
// fp8 e4m3 GEMM, energy only (trial hopfield). smem: 2x4096 + 2x4096 B
// + ered at +16384. K=768, xi8 pre-scaled x16 -> energy * 1/256.
// ------------------------------------------------------------------
__device__ __forceinline__ void dev_gemm_fp8(
    char* smem, const unsigned char* __restrict__ A0,
    const unsigned char* __restrict__ B0, double* __restrict__ ep,
    int my, int nx, int tid)
{
  unsigned char* As = (unsigned char*)smem;
  unsigned char* Bs = (unsigned char*)smem + 8192;
  double* ered = (double*)(smem + 16384);
  int lane = tid & 63, w = tid >> 6;
  int wm = (w & 1) << 6, wn = (w >> 1) << 6;
  int m0 = my * 128, n0 = nx * 128;

  v4f acc[4][4];
  acc_zero(acc);

  int srow = tid >> 1;
  int sc16 = (tid & 1) ^ ((srow >> 2) & 1);
  const int nk = DIM >> 5;   // 24
#define STAGE8(buf, k0)                                                          \
  do {                                                                           \
    __builtin_amdgcn_global_load_lds(                                            \
        (__attribute__((address_space(1))) uint32_t*)(A0 + (size_t)(m0 + srow) * DIM + (k0) + (sc16 << 4)), \
        (__attribute__((address_space(3))) uint32_t*)(As + ((buf) << 12) + (w << 10)), 16, 0, 0); \
    __builtin_amdgcn_global_load_lds(                                            \
        (__attribute__((address_space(1))) uint32_t*)(B0 + (size_t)(n0 + srow) * DIM + (k0) + (sc16 << 4)), \
        (__attribute__((address_space(3))) uint32_t*)(Bs + ((buf) << 12) + (w << 10)), 16, 0, 0); \
  } while (0)

  STAGE8(0, 0);
  for (int kt = 0; kt < nk; kt++) {
    __syncthreads();
    int nxt = kt + 1;
    if (nxt < nk) STAGE8(nxt & 1, nxt << 5);
    const unsigned char* Ac = As + ((kt & 1) << 12);
    const unsigned char* Bc = Bs + ((kt & 1) << 12);
    int mrow = lane & 15, q = lane >> 4;
    long af[4], bfr[4];
#pragma unroll
    for (int i = 0; i < 4; i++) {
      int rA = wm + (i << 4) + mrow;
      int rB = wn + (i << 4) + mrow;
      int qa = q ^ (((rA >> 2) & 1) << 1);
      int qb = q ^ (((rB >> 2) & 1) << 1);
      af[i]  = *(const long*)(Ac + rA * 32 + (qa << 3));
      bfr[i] = *(const long*)(Bc + rB * 32 + (qb << 3));
    }
#pragma unroll
    for (int i = 0; i < 4; i++)
#pragma unroll
      for (int j = 0; j < 4; j++)
        acc[i][j] = __builtin_amdgcn_mfma_f32_16x16x32_fp8_fp8(af[i], bfr[j], acc[i][j], 0, 0, 0);
  }
#undef STAGE8

  float e = 0.f;
#pragma unroll
  for (int i = 0; i < 4; i++)
#pragma unroll
    for (int j = 0; j < 4; j++)
#pragma unroll
      for (int r = 0; r < 4; r++) {
        float v = acc[i][j][r];
        v = v > 0.f ? v : 0.f;
        e += v * v;
      }
  for (int o = 32; o; o >>= 1) e += __shfl_xor(e, o, 64);
  if (lane == 0) ered[w] = (double)e;
  __syncthreads();
  if (tid == 0) {
    double tot = (ered[0] + ered[1]) + (ered[2] + ered[3]);
    int tt = my / 13, ry = my - tt * 13;
    ep[EP_HOPT + tt * 312 + ry * 24 + nx] = (-0.5 / 256.0) * tot;
  }
}

// ------------------------------------------------------------------
// MFMA attention forward (device). smem: Ks 29952 | Qs 29952 | er 32.
// SP=1: store P (+ pad-zero cols). ep_slot gets the energy partial.
// ------------------------------------------------------------------
template <int SP>
__device__ __forceinline__ void dev_attn_fwd(
    char* smem, const __bf16* __restrict__ Kp, const __bf16* __restrict__ Qp,
    __bf16* __restrict__ P, size_t Pbase, double* __restrict__ ep_slot, int tid)
{
  __bf16* Ks = (__bf16*)smem;
  __bf16* Qs = (__bf16*)smem + PROWS * 72;
  double* er = (double*)(smem + 59904);

  for (int i = tid; i < PROWS * 8; i += 256) {
    int row = i >> 3, c = i & 7;
    v8bf kv = zero8(), qv = zero8();
    if (row < SEQ) {
      kv = *(const v8bf*)(Kp + (size_t)row * DIM + c * 8);
      qv = *(const v8bf*)(Qp + (size_t)row * DIM + c * 8);
    }
    *(v8bf*)(Ks + row * 72 + c * 8) = kv;
    *(v8bf*)(Qs + row * 72 + c * 8) = qv;
  }
  __syncthreads();

  int lane = tid & 63, w = tid >> 6;
  int mrow = lane & 15, quad = lane >> 4, ncol = mrow;
  int ksel = quad * 8;
  v4f zero = {0.f, 0.f, 0.f, 0.f};
  double eacc = 0.0;

  for (int mt = w; mt < 13; mt += 4) {
    int m0 = mt * 16;
    v8bf af0 = *(const v8bf*)(Qs + (m0 + mrow) * 72 + ksel);
    v8bf af1 = *(const v8bf*)(Qs + (m0 + mrow) * 72 + 32 + ksel);
    v4f acc[13];
#pragma unroll
    for (int j = 0; j < 13; j++) {
      v8bf bf0 = *(const v8bf*)(Ks + (j * 16 + mrow) * 72 + ksel);
      v8bf bf1 = *(const v8bf*)(Ks + (j * 16 + mrow) * 72 + 32 + ksel);
      v4f t = __builtin_amdgcn_mfma_f32_16x16x32_bf16(af0, bf0, zero, 0, 0, 0);
      acc[j] = __builtin_amdgcn_mfma_f32_16x16x32_bf16(af1, bf1, t, 0, 0, 0);
    }
    float mx[4] = {-1e30f, -1e30f, -1e30f, -1e30f};
#pragma unroll
    for (int j = 0; j < 13; j++) {
      bool colv = (j < 12) || (ncol < 4);
#pragma unroll
      for (int r = 0; r < 4; r++) {
        float sv = colv ? BETA_F * acc[j][r] : -1e30f;
        acc[j][r] = sv;
        mx[r] = fmaxf(mx[r], sv);
      }
    }
#pragma unroll
    for (int o = 1; o < 16; o <<= 1)
#pragma unroll
      for (int r = 0; r < 4; r++) mx[r] = fmaxf(mx[r], __shfl_xor(mx[r], o, 64));
    float zr[4] = {0.f, 0.f, 0.f, 0.f};
#pragma unroll
    for (int j = 0; j < 13; j++)
#pragma unroll
      for (int r = 0; r < 4; r++) {
        float t = (acc[j][r] > -1e29f) ? expf(acc[j][r] - mx[r]) : 0.f;
        acc[j][r] = t;
        zr[r] += t;
      }
#pragma unroll
    for (int o = 1; o < 16; o <<= 1)
#pragma unroll
      for (int r = 0; r < 4; r++) zr[r] += __shfl_xor(zr[r], o, 64);
    if (ncol == 0) {
#pragma unroll
      for (int r = 0; r < 4; r++) {
        int q = m0 + quad * 4 + r;
        if (q < SEQ) eacc += (double)(mx[r] + logf(zr[r]));
      }
    }
    if (SP) {
      float inv[4];
#pragma unroll
      for (int r = 0; r < 4; r++) inv[r] = 1.f / zr[r];
      size_t Pb = Pbase + (size_t)(m0 + quad * 4) * PCOLS;
#pragma unroll
      for (int j = 0; j < 13; j++)
#pragma unroll
        for (int r = 0; r < 4; r++) {
          int q = m0 + quad * 4 + r;
          float pv = (q < SEQ) ? acc[j][r] * inv[r] : 0.f;
          P[Pb + (size_t)r * PCOLS + j * 16 + ncol] = (__bf16)pv;
        }
#pragma unroll
      for (int r = 0; r < 4; r++)
        P[Pb + (size_t)r * PCOLS + 208 + ncol] = (__bf16)0.f;
    }
  }
  for (int o = 32; o; o >>= 1) eacc += __shfl_xor(eacc, o, 64);
  if (lane == 0) er[w] = eacc;
  __syncthreads();
  if (tid == 0)
    *ep_slot = -(double)INV_BETA * ((er[0] + er[1]) + (er[2] + er[3]));
}

// ------------------------------------------------------------------
// MFMA attention backward one side (device). smem: BT 29696 B.
// z=0: dQ = -(P@K); z=1: dK = -(PT@Q)
// ------------------------------------------------------------------
__device__ __forceinline__ void dev_attn_bwd(
    char* smem, const __bf16* __restrict__ Kb, const __bf16* __restrict__ Qb,
    const __bf16* __restrict__ Pg, const __bf16* __restrict__ PTg,
    __bf16* __restrict__ dQg, __bf16* __restrict__ dKg,
    int bh, int z, int tid)
{
  __bf16* BT = (__bf16*)smem;   // 64 x 232
  int b = bh / HN, h = bh - b * HN;
  const __bf16* Bsrc = (z ? Qb : Kb) + (size_t)(b * SEQ) * DIM + h * YD;
  const __bf16* Asrc = (z ? PTg : Pg) + (size_t)bh * PAREA;
  __bf16* Dst = (z ? dKg : dQg) + (size_t)(b * SEQ) * DIM + h * YD;
  for (int i = tid; i < 64 * 232 / 8; i += 256) ((v8bf*)BT)[i] = zero8();
  __syncthreads();
  for (int i = tid; i < SEQ * 8; i += 256) {
    int k = i >> 3, c = i & 7;
    v8bf v = *(const v8bf*)(Bsrc + (size_t)k * DIM + c * 8);
#pragma unroll
    for (int e = 0; e < 8; e++) BT[(c * 8 + e) * 232 + k] = v[e];
  }
  __syncthreads();

  int lane = tid & 63, w = tid >> 6;
  int mrow = lane & 15, quad = lane >> 4, ncol = mrow;
  int ksel = quad * 8;
  for (int mt = w; mt < 13; mt += 4) {
    int m0 = mt * 16;
    v4f acc[4];
    v4f zero = {0.f, 0.f, 0.f, 0.f};
#pragma unroll
    for (int n = 0; n < 4; n++) acc[n] = zero;
#pragma unroll
    for (int s = 0; s < 7; s++) {
      v8bf af = *(const v8bf*)(Asrc + (size_t)(m0 + mrow) * PCOLS + s * 32 + ksel);
#pragma unroll
      for (int n = 0; n < 4; n++) {
        v8bf bf = *(const v8bf*)(BT + (n * 16 + mrow) * 232 + s * 32 + ksel);
        acc[n] = __builtin_amdgcn_mfma_f32_16x16x32_bf16(af, bf, acc[n], 0, 0, 0);
      }
    }
    int row = m0 + quad * 4;
#pragma unroll
    for (int n = 0; n < 4; n++)
#pragma unroll
      for (int r = 0; r < 4; r++)
        if (row + r < SEQ)
          Dst[(size_t)(row + r) * DIM + n * 16 + ncol] = (__bf16)(-acc[n][r]);
  }
}

// ------------------------------------------------------------------
// ptrans whole-bh (device): 49 x (32x32) tiles through LDS.
// ------------------------------------------------------------------
__device__ __forceinline__ void dev_ptrans(
    char* smem, const __bf16* __restrict__ Pg, __bf16* __restrict__ PTg,
    int bh, int tid)
{
  __bf16 (*t)[33] = (__bf16(*)[33])smem;
  const __bf16* Pb = Pg + (size_t)bh * PAREA;
  __bf16* PTb = PTg + (size_t)bh * PAREA;
  int tx = tid & 31, ty = tid >> 5;
  for (int q0 = 0; q0 < PCOLS; q0 += 32)
    for (int k0 = 0; k0 < PCOLS; k0 += 32) {
      __syncthreads();
      for (int rr = ty; rr < 32; rr += 8)
        t[rr][tx] = (q0 + rr < PROWS) ? Pb[(size_t)(q0 + rr) * PCOLS + k0 + tx] : (__bf16)0.f;
      __syncthreads();
      for (int rr = ty; rr < 32; rr += 8)
        if (k0 + rr < PROWS)
          PTb[(size_t)(k0 + rr) * PCOLS + q0 + tx] = t[tx][rr];
    }
}

// ==================================================================
// Dispatch 1: prep = ln_fwd(1568) | cvtall(3456) | cvtT(3456) | init(288)
// ==================================================================
__global__ __launch_bounds__(256) void prep_k(
    const float* __restrict__ x, const float* __restrict__ gamma,
    const float* __restrict__ delta, const float* __restrict__ wk,
    const float* __restrict__ wq, const float* __restrict__ xi,
    __bf16* __restrict__ g, float* __restrict__ xhat, float* __restrict__ rstd,
    __bf16* __restrict__ wk_bf, __bf16* __restrict__ wq_bf,
    __bf16* __restrict__ xi_bf, int* __restrict__ xi8,
    __bf16* __restrict__ wkT, __bf16* __restrict__ wqT, __bf16* __restrict__ xiT,
    __bf16* __restrict__ gt, unsigned char* __restrict__ g8,
    __bf16* __restrict__ dq, __bf16* __restrict__ dk)
{
  __shared__ float s[4];
  __shared__ float tt[32][33];
  int blk = blockIdx.x, tid = threadIdx.x;
  if (blk < 1568) {
    int tok = blk;
    const float* xp = x + (size_t)tok * DIM;
    float v0 = xp[tid], v1 = xp[tid + 256], v2 = xp[tid + 512];
    float sum = v0 + v1 + v2;
    for (int o = 32; o; o >>= 1) sum += __shfl_xor(sum, o, 64);
    if ((tid & 63) == 0) s[tid >> 6] = sum;
    __syncthreads();
    float mu = (s[0] + s[1] + s[2] + s[3]) * (1.0f / DIM);
    __syncthreads();
    float d0 = v0 - mu, d1 = v1 - mu, d2 = v2 - mu;
    float sq = d0 * d0 + d1 * d1 + d2 * d2;
    for (int o = 32; o; o >>= 1) sq += __shfl_xor(sq, o, 64);
    if ((tid & 63) == 0) s[tid >> 6] = sq;
    __syncthreads();
    float var = (s[0] + s[1] + s[2] + s[3]) * (1.0f / DIM);
    float r = rsqrtf(var + LN_EPS_F);
    float xh0 = d0 * r, xh1 = d1 * r, xh2 = d2 * r;
    size_t base = (size_t)tok * DIM;
    g[base + tid]       = (__bf16)(gamma[tid] * xh0 + delta[tid]);
    g[base + tid + 256] = (__bf16)(gamma[tid + 256] * xh1 + delta[tid + 256]);
    g[base + tid + 512] = (__bf16)(gamma[tid + 512] * xh2 + delta[tid + 512]);
    xhat[base + tid] = xh0; xhat[base + tid + 256] = xh1; xhat[base + tid + 512] = xh2;
    if (tid == 0) rstd[tok] = r;
  } else if (blk < 5024) {
    const int W4 = DIM * DIM / 4;
    const int X4 = MXI * DIM / 4;
    int i = (blk - 1568) * 256 + tid;
    if (i < W4) {
      float4 v = ((const float4*)wk)[i];
      v4bf o = { (__bf16)v.x, (__bf16)v.y, (__bf16)v.z, (__bf16)v.w };
      *(v4bf*)(wk_bf + 4 * (size_t)i) = o;
    } else if (i < 2 * W4) {
      int j = i - W4;
      float4 v = ((const float4*)wq)[j];
      v4bf o = { (__bf16)v.x, (__bf16)v.y, (__bf16)v.z, (__bf16)v.w };
      *(v4bf*)(wq_bf + 4 * (size_t)j) = o;
    } else if (i < 2 * W4 + X4) {
      int j = i - 2 * W4;
      float4 v = ((const float4*)xi)[j];
      v4bf o = { (__bf16)v.x, (__bf16)v.y, (__bf16)v.z, (__bf16)v.w };
      *(v4bf*)(xi_bf + 4 * (size_t)j) = o;
      int pk = __builtin_amdgcn_cvt_pk_fp8_f32(16.f * v.x, 16.f * v.y, 0, false);
      pk = __builtin_amdgcn_cvt_pk_fp8_f32(16.f * v.z, 16.f * v.w, pk, true);
      xi8[j] = pk;
    }
  } else if (blk < 8480) {
    int job = blk - 5024;
    const float* src; __bf16* dst; int R; float scale; int r0, c0;
    if (job < 576)       { src = wk; dst = wkT; R = DIM; scale = 1.f;  int j = job;        c0 = (j % 24) * 32; r0 = (j / 24) * 32; }
    else if (job < 1152) { src = wq; dst = wqT; R = DIM; scale = 1.f;  int j = job - 576;  c0 = (j % 24) * 32; r0 = (j / 24) * 32; }
    else                 { src = xi; dst = xiT; R = MXI; scale = -1.f; int j = job - 1152; c0 = (j % 24) * 32; r0 = (j / 24) * 32; }
    int tx = tid & 31, ty = tid >> 5;
    for (int rr = ty; rr < 32; rr += 8)
      tt[rr][tx] = src[(size_t)(r0 + rr) * DIM + c0 + tx];
    __syncthreads();
    for (int rr = ty; rr < 32; rr += 8)
      dst[(size_t)(c0 + rr) * R + r0 + tx] = (__bf16)(scale * tt[tx][rr]);
  } else {
    int i = (blk - 8480) * 256 + tid;
    const int PADN = (MPAD - TOK) * DIM;   // 73728
    if (i < PADN) {
      size_t o = (size_t)TOK * DIM + i;
      g[o] = (__bf16)0.f; dq[o] = (__bf16)0.f; dk[o] = (__bf16)0.f;
#pragma unroll
      for (int t = 0; t < 4; t++) {
        gt[(size_t)t * MPAD * DIM + o] = (__bf16)0.f;
        g8[(size_t)t * MPAD * DIM + o] = 0;
      }
    }
  }
}

// ==================================================================
// Dispatch 2: base KQ GEMM. grid (6,13,2)
// ==================================================================
__global__ __launch_bounds__(256, 4) void kqbase_k(
    const __bf16* __restrict__ g, const __bf16* __restrict__ wk,
    const __bf16* __restrict__ wq, __bf16* __restrict__ Kb, __bf16* __restrict__ Qb)
{
  __shared__ __align__(16) char smem[32768];
  int tid = threadIdx.x;
  int m0 = blockIdx.y * 128, n0 = blockIdx.x * 128;
  const __bf16* B = blockIdx.z ? wq : wk;
  __bf16* C = blockIdx.z ? Qb : Kb;
  v4f acc[4][4];
  acc_zero(acc);
  gemm_core_bf16(smem, g, DIM, B, DIM, m0, n0, 0, DIM >> 5, acc, tid);
  epi_store_bf16(acc, C, DIM, m0, n0, tid);
}

// ==================================================================
// Dispatch 3: fwdbase = attn base (96) | hop base (312). grid 408.
// ==================================================================
__global__ __launch_bounds__(256, 2) void fwdbase_k(
    const __bf16* __restrict__ Kb, const __bf16* __restrict__ Qb,
    __bf16* __restrict__ P, const __bf16* __restrict__ g,
    const __bf16* __restrict__ xi, __bf16* __restrict__ rh,
    double* __restrict__ ep)
{
  __shared__ __align__(16) char smem[59936];
  int blk = blockIdx.x, tid = threadIdx.x;
  if (blk < 96) {
    int bh = blk, b = bh / HN, h = bh - b * HN;
    const __bf16* Kp = Kb + (size_t)(b * SEQ) * DIM + h * YD;
    const __bf16* Qp = Qb + (size_t)(b * SEQ) * DIM + h * YD;
    dev_attn_fwd<1>(smem, Kp, Qp, P, (size_t)bh * PAREA, ep + bh, tid);
  } else {
    int j = blk - 96;
    int ry = j / 24, nx = j - ry * 24;
    v4f acc[4][4];
    acc_zero(acc);
    gemm_core_bf16(smem, g, DIM, xi, DIM, ry * 128, nx * 128, 0, DIM >> 5, acc, tid);
    epi_relu_energy(acc, rh, MXI, ry * 128, nx * 128, tid,
                    (double*)(smem + 59904), ep + EP_HOPB + ry * 24 + nx);
  }
}

// ==================================================================
// Dispatch 4: bwd1 = ptrans (96) | attn_bwd z0 (96) | rh@xiT (156). grid 348.
// ==================================================================
__global__ __launch_bounds__(256, 4) void bwd1_k(
    const __bf16* __restrict__ Kb, const __bf16* __restrict__ Qb,
    const __bf16* __restrict__ P, __bf16* __restrict__ PT,
    __bf16* __restrict__ dQg, __bf16* __restrict__ dKg,
    const __bf16* __restrict__ rh, const __bf16* __restrict__ xiT,
    float* __restrict__ dGp1, float* __restrict__ dGp2)
{
  __shared__ __align__(16) char smem[32768];
  int blk = blockIdx.x, tid = threadIdx.x;
  if (blk < 96) {
    dev_ptrans(smem, P, PT, blk, tid);
  } else if (blk < 192) {
    dev_attn_bwd(smem, Kb, Qb, P, PT, dQg, dKg, blk - 96, 0, tid);
  } else {
    int j = blk - 192;          // 0..155
    int half = j / 78, jj = j - half * 78;
    int my = jj / 6, nx = jj - my * 6;
    v4f acc[4][4];
    acc_zero(acc);
    gemm_core_bf16(smem, rh, MXI, xiT, MXI, my * 128, nx * 128,
                   half * 1536, 48, acc, tid);
    epi_store_f32(acc, half ? dGp2 : dGp1, my * 128, nx * 128, tid);
  }
}

// ==================================================================
// Dispatch 5: bwd2 = attn_bwd z1 (96) | dQg@wqT (78). grid 174.
// ==================================================================
__global__ __launch_bounds__(256, 4) void bwd2_k(
    const __bf16* __restrict__ Kb, const __bf16* __restrict__ Qb,
    const __bf16* __restrict__ P, const __bf16* __restrict__ PT,
    __bf16* __restrict__ dQg, __bf16* __restrict__ dKg,
    const __bf16* __restrict__ wqT, float* __restrict__ dGp0)
{
  __shared__ __align__(16) char smem[32768];
  int blk = blockIdx.x, tid = threadIdx.x;
  if (blk < 96) {
    dev_attn_bwd(smem, Kb, Qb, P, (__bf16*)PT, dQg, dKg, blk, 1, tid);
  } else {
    int j = blk - 96;
    int my = j / 6, nx = j - my * 6;
    v4f acc[4][4];
    acc_zero(acc);
    gemm_core_bf16(smem, dQg, DIM, wqT, DIM, my * 128, nx * 128, 0, DIM >> 5, acc, tid);
    epi_store_f32(acc, dGp0, my * 128, nx * 128, tid);
  }
}

// ==================================================================
// Dispatch 6: bwd3 = dKg@wkT (78 blocks)
// ==================================================================
__global__ __launch_bounds__(256, 4) void bwd3_k(
    const __bf16* __restrict__ dKg, const __bf16* __restrict__ wkT,
    float* __restrict__ dGp3)
{
  __shared__ __align__(16) char smem[32768];
  int tid = threadIdx.x;
  int my = blockIdx.x / 6, nx = blockIdx.x - my * 6;
  v4f acc[4][4];
  acc_zero(acc);
  gemm_core_bf16(smem, dKg, DIM, wkT, DIM, my * 128, nx * 128, 0, DIM >> 5, acc, tid);
  epi_store_f32(acc, dGp3, my * 128, nx * 128, tid);
}

// ==================================================================
// Dispatch 7: fused LN-backward + trial axpy+LN. grid 1568.
// ==================================================================
__global__ __launch_bounds__(256) void lnbwd_axpy_k(
    const float* __restrict__ p0, const float* __restrict__ p1,
    const float* __restrict__ p2, const float* __restrict__ p3,
    const float* __restrict__ xhat, const float* __restrict__ rstd,
    const float* __restrict__ gamma, const float* __restrict__ delta,
    const float* __restrict__ x, float* __restrict__ grad,
    __bf16* __restrict__ gt, unsigned char* __restrict__ g8)
{
  __shared__ float s[8];
  int tok = blockIdx.x, tid = threadIdx.x;
  size_t base = (size_t)tok * DIM;
  float ga0 = gamma[tid], ga1 = gamma[tid + 256], ga2 = gamma[tid + 512];
  float de0 = delta[tid], de1 = delta[tid + 256], de2 = delta[tid + 512];
  float g0 = p0[base + tid]       + p1[base + tid]       + p2[base + tid]       + p3[base + tid];
  float g1 = p0[base + tid + 256] + p1[base + tid + 256] + p2[base + tid + 256] + p3[base + tid + 256];
  float g2 = p0[base + tid + 512] + p1[base + tid + 512] + p2[base + tid + 512] + p3[base + tid + 512];
  float dh0 = g0 * ga0, dh1 = g1 * ga1, dh2 = g2 * ga2;
  float xh0 = xhat[base + tid], xh1 = xhat[base + tid + 256], xh2 = xhat[base + tid + 512];
  float s1 = dh0 + dh1 + dh2;
  float s2 = dh0 * xh0 + dh1 * xh1 + dh2 * xh2;
  for (int o = 32; o; o >>= 1) { s1 += __shfl_xor(s1, o, 64); s2 += __shfl_xor(s2, o, 64); }
  if ((tid & 63) == 0) { s[tid >> 6] = s1; s[4 + (tid >> 6)] = s2; }
  __syncthreads();
  float m1 = (s[0] + s[1] + s[2] + s[3]) * (1.0f / DIM);
  float m2 = (s[4] + s[5] + s[6] + s[7]) * (1.0f / DIM);
  float r = rstd[tok];
  float gr0 = r * (dh0 - m1 - xh0 * m2);
  float gr1 = r * (dh1 - m1 - xh1 * m2);
  float gr2 = r * (dh2 - m1 - xh2 * m2);
  grad[base + tid] = gr0; grad[base + tid + 256] = gr1; grad[base + tid + 512] = gr2;
  float xv0 = x[base + tid], xv1 = x[base + tid + 256], xv2 = x[base + tid + 512];
#pragma unroll
  for (int t = 0; t < 4; t++) {
    float lr = 1.0f / (float)(1 << t);
    float v0 = xv0 - lr * gr0, v1 = xv1 - lr * gr1, v2 = xv2 - lr * gr2;
    float sum = v0 + v1 + v2;
    for (int o = 32; o; o >>= 1) sum += __shfl_xor(sum, o, 64);
    __syncthreads();
    if ((tid & 63) == 0) s[tid >> 6] = sum;
    __syncthreads();
    float mu = (s[0] + s[1] + s[2] + s[3]) * (1.0f / DIM);
    float d0 = v0 - mu, d1 = v1 - mu, d2 = v2 - mu;
    float sq = d0 * d0 + d1 * d1 + d2 * d2;
    for (int o = 32; o; o >>= 1) sq += __shfl_xor(sq, o, 64);
    __syncthreads();
    if ((tid & 63) == 0) s[tid >> 6] = sq;
    __syncthreads();
    float var = (s[0] + s[1] + s[2] + s[3]) * (1.0f / DIM);
    float r2 = rsqrtf(var + LN_EPS_F);
    float o0 = ga0 * (d0 * r2) + de0;
    float o1 = ga1 * (d1 * r2) + de1;
    float o2 = ga2 * (d2 * r2) + de2;
    size_t ob = ((size_t)t * MPAD + tok) * DIM;
    gt[ob + tid] = (__bf16)o0; gt[ob + tid + 256] = (__bf16)o1; gt[ob + tid + 512] = (__bf16)o2;
    g8[ob + tid]       = (unsigned char)(__builtin_amdgcn_cvt_pk_fp8_f32(o0, o0, 0, false) & 0xff);
    g8[ob + tid + 256] = (unsigned char)(__builtin_amdgcn_cvt_pk_fp8_f32(o1, o1, 0, false) & 0xff);
    g8[ob + tid + 512] = (unsigned char)(__builtin_amdgcn_cvt_pk_fp8_f32(o2, o2, 0, false) & 0xff);
  }
}

// ==================================================================
// Dispatch 8: trial1 = trial KQ (624 jobs) + fp8 trial hop (1248 jobs),
// 936 blocks x 2 jobs each (balanced, single round).
// ==================================================================
__global__ __launch_bounds__(256, 4) void trial1_k(
    const __bf16* __restrict__ gt, const __bf16* __restrict__ wk,
    const __bf16* __restrict__ wq, __bf16* __restrict__ KbT, __bf16* __restrict__ QbT,
    const unsigned char* __restrict__ g8, const unsigned char* __restrict__ xi8,
    double* __restrict__ ep)
{
  __shared__ __align__(16) char smem[32800];
  int tid = threadIdx.x;
#pragma unroll
  for (int jj = 0; jj < 2; jj++) {
    int id = blockIdx.x + jj * 936;
    __syncthreads();
    if (id < 624) {
      int z = id / 312, rr = id - z * 312;
      int my = rr / 6, nx = rr - my * 6;
      const __bf16* B = z ? wq : wk;
      __bf16* C = z ? QbT : KbT;
      v4f acc[4][4];
      acc_zero(acc);
      gemm_core_bf16(smem, gt, DIM, B, DIM, my * 128, nx * 128, 0, DIM >> 5, acc, tid);
      epi_store_bf16(acc, C, DIM, my * 128, nx * 128, tid);
    } else {
      int j = id - 624;
      int my = j / 24, nx = j - my * 24;
      dev_gemm_fp8(smem, g8, xi8, ep, my, nx, tid);
    }
  }
}

// ==================================================================
// Dispatch 9: trial attention. grid (96, 4).
// ==================================================================
__global__ __launch_bounds__(256) void attn_trial_k(
    const __bf16* __restrict__ Kt, const __bf16* __restrict__ Qt,
    double* __restrict__ ep)
{
  __shared__ __align__(16) char smem[59936];
  int bh = blockIdx.x, t = blockIdx.y, tid = threadIdx.x;
  int b = bh / HN, h = bh - b * HN;
  size_t voff = (size_t)t * MPAD * DIM;
  const __bf16* Kp = Kt + voff + (size_t)(b * SEQ) * DIM + h * YD;
  const __bf16* Qp = Qt + voff + (size_t)(b * SEQ) * DIM + h * YD;
  dev_attn_fwd<0>(smem, Kp, Qp, (__bf16*)nullptr, 0, ep + (t + 1) * 96 + bh, tid);
}

// ==================================================================
// Dispatch 10: fused reduce+choose+update. grid 624 (grid-stride).
// ==================================================================
__global__ __launch_bounds__(256) void update_k(
    const float* __restrict__ x, const float* __restrict__ grad,
    const double* __restrict__ ep, float* __restrict__ out, int n4)
{
  __shared__ double sm[4];
  __shared__ float chs;
  int tid = threadIdx.x;
  double e[5];
  for (int s = 0; s < 5; s++) {
    double acc = 0.0;
    int a0 = 96 * s;
    for (int i = tid; i < 96; i += 256) acc += ep[a0 + i];
    int b0 = (s == 0) ? EP_HOPB : EP_HOPT + 312 * (s - 1);
    for (int i = tid; i < 312; i += 256) acc += ep[b0 + i];
    for (int o = 32; o; o >>= 1) acc += __shfl_xor(acc, o, 64);
    if ((tid & 63) == 0) sm[tid >> 6] = acc;
    __syncthreads();
    e[s] = (sm[0] + sm[1]) + (sm[2] + sm[3]);
    __syncthreads();
  }
  if (tid == 0) {
    double e0 = e[0];
    float c = 0.0625f;
    if (e[4] < e0) c = 0.125f;
    if (e[3] < e0) c = 0.25f;
    if (e[2] < e0) c = 0.5f;
    if (e[1] < e0) c = 1.0f;
    chs = c;
  }
  __syncthreads();
  float lr = chs;
  for (int i = blockIdx.x * 256 + tid; i < n4; i += gridDim.x * 256) {
    const float4 xv = ((const float4*)x)[i];
    const float4 gv = ((const float4*)grad)[i];
    float4 o;
    o.x = xv.x - lr * gv.x; o.y = xv.y - lr * gv.y;
    o.z = xv.z - lr * gv.z; o.w = xv.w - lr * gv.w;
    ((float4*)out)[i] = o;
  }
}

// ------------------------------------------------------------------
extern "C" void kernel_launch(void* const* d_in, const int* in_sizes, int n_in,
                              void* d_out, int out_size, void* d_ws, size_t ws_size,
                              hipStream_t stream)
{
  const float* x     = (const float*)d_in[0];
  const float* gamma = (const float*)d_in[1];
  const float* delta = (const float*)d_in[2];
  const float* wk    = (const float*)d_in[3];
  const float* wq    = (const float*)d_in[4];
  const float* xi    = (const float*)d_in[5];
  float* out = (float*)d_out;

  const size_t NE = (size_t)TOK * DIM;
  const size_t NP = (size_t)MPAD * DIM;

  double* eparts = (double*)d_ws;                // 2040 doubles
  float* fp = (float*)(eparts + EP_TOTAL + 8);
  float* xhat = fp;  fp += NE;
  float* grad = fp;  fp += NE;
  float* rstd = fp;  fp += TOK;
  fp += 16;
  __bf16* bp = (__bf16*)(((uintptr_t)fp + 15) & ~(uintptr_t)15);
  __bf16* g_bf   = bp;  bp += NP;
  __bf16* g_tr   = bp;  bp += 4 * NP;
  __bf16* Kb_bf  = bp;  bp += NP;
  __bf16* Qb_bf  = bp;  bp += NP;
  __bf16* dQg_bf = bp;  bp += NP;
  __bf16* dKg_bf = bp;  bp += NP;
  __bf16* rh_bf  = bp;  bp += (size_t)MPAD * MXI;
  __bf16* wk_bf  = bp;  bp += (size_t)DIM * DIM;
  __bf16* wq_bf  = bp;  bp += (size_t)DIM * DIM;
  __bf16* wkT_bf = bp;  bp += (size_t)DIM * DIM;
  __bf16* wqT_bf = bp;  bp += (size_t)DIM * DIM;
  __bf16* xi_bf  = bp;  bp += (size_t)MXI * DIM;
  __bf16* xiT_bf = bp;  bp += (size_t)DIM * MXI;
  __bf16* P_bf   = bp;  bp += (size_t)96 * PAREA;
  __bf16* PT_bf  = bp;  bp += (size_t)96 * PAREA;
  __bf16* KbT_bf = bp;  bp += 4 * NP;
  __bf16* QbT_bf = bp;  bp += 4 * NP;
  unsigned char* g8  = (unsigned char*)bp;  bp += 2 * NP;              // 4*NP bytes
  unsigned char* xi8 = (unsigned char*)bp;  bp += (size_t)MXI * DIM / 2;
  // dG split-K partials (4 x NP floats = 16 NP bytes) alias KbT+QbT
  // (8NP + 8NP bytes); consumed by lnbwd_axpy BEFORE trial1 overwrites.
  float* dGp0 = (float*)KbT_bf;
  float* dGp1 = dGp0 + NP;
  float* dGp2 = dGp1 + NP;
  float* dGp3 = dGp2 + NP;

  const int n4 = (int)(NE / 4);
  dim3 blk(256);

  // 1. prep
  hipLaunchKernelGGL(prep_k, dim3(8768), blk, 0, stream,
                     x, gamma, delta, wk, wq, xi,
                     g_bf, xhat, rstd, wk_bf, wq_bf, xi_bf, (int*)xi8,
                     wkT_bf, wqT_bf, xiT_bf, g_tr, g8, dQg_bf, dKg_bf);
  // 2. base KQ
  hipLaunchKernelGGL(kqbase_k, dim3(6, 13, 2), blk, 0, stream,
                     g_bf, wk_bf, wq_bf, Kb_bf, Qb_bf);
  // 3. base attn + base hopfield
  hipLaunchKernelGGL(fwdbase_k, dim3(408), blk, 0, stream,
                     Kb_bf, Qb_bf, P_bf, g_bf, xi_bf, rh_bf, eparts);
  // 4. ptrans + attn_bwd(dQ) + rh@xiT
  hipLaunchKernelGGL(bwd1_k, dim3(348), blk, 0, stream,
                     Kb_bf, Qb_bf, P_bf, PT_bf, dQg_bf, dKg_bf,
                     rh_bf, xiT_bf, dGp1, dGp2);
  // 5. attn_bwd(dK) + dQg@wqT
  hipLaunchKernelGGL(bwd2_k, dim3(174), blk, 0, stream,
                     Kb_bf, Qb_bf, P_bf, PT_bf, dQg_bf, dKg_bf, wqT_bf, dGp0);
  // 6. dKg@wkT
  hipLaunchKernelGGL(bwd3_k, dim3(78), blk, 0, stream, dKg_bf, wkT_bf, dGp3);
  // 7. ln_bwd + trial axpy/LN fused
  hipLaunchKernelGGL(lnbwd_axpy_k, dim3(TOK), blk, 0, stream,
                     dGp0, dGp1, dGp2, dGp3, xhat, rstd, gamma, delta, x,
                     grad, g_tr, g8);
  // 8. trial KQ + fp8 trial hopfield (balanced merge)
  hipLaunchKernelGGL(trial1_k, dim3(936), blk, 0, stream,
                     g_tr, wk_bf, wq_bf, KbT_bf, QbT_bf, g8, xi8, eparts);
  // 9. trial attention
  hipLaunchKernelGGL(attn_trial_k, dim3(96, 4), blk, 0, stream,
                     KbT_bf, QbT_bf, eparts);
  // 10. reduce + choose + update
  hipLaunchKernelGGL(update_k, dim3(624), blk, 0, stream,
                     x, grad, eparts, out, n4);
}

// Round 9
// 306.696 us; speedup vs baseline: 1.0970x; 1.0970x over previous
//
#include <hip/hip_runtime.h>
#include <math.h>

#define TOK 1568      // B*N = 8*196
#define MPAD 1664     // 13 * 128
#define DIM 768
#define HN 12
#define SEQ 196
#define YD 64
#define MXI 3072
#define BETA_F 0.125f
#define INV_BETA 8.0f
#define LN_EPS_F 1e-5f

// P/PT padded geometry: rows 208 (13*16), cols 224 (7*32)
#define PROWS 208
#define PCOLS 224
#define PAREA (PROWS * PCOLS)

// energy partials (doubles): attn ver*96+bh, ver 0..4 -> [0,480)
// hop base [480,792) ; hop trial t*312 -> [792,2040)
#define EP_HOPB 480
#define EP_HOPT 792
#define EP_TOTAL 2040

#define NPE ((size_t)MPAD * DIM)

// fused-attn LDS layout (bytes)
#define OFF_QS 29952
#define OFF_BK 59904
#define OFF_BQ 68096
#define OFF_ER 76288
#define SM_ATTN 76352

typedef __bf16 v8bf __attribute__((ext_vector_type(8)));
typedef __bf16 v4bf __attribute__((ext_vector_type(4)));
typedef float  v4f  __attribute__((ext_vector_type(4)));

__device__ __forceinline__ v8bf zero8() {
  v8bf v = { (__bf16)0.f, (__bf16)0.f, (__bf16)0.f, (__bf16)0.f,
             (__bf16)0.f, (__bf16)0.f, (__bf16)0.f, (__bf16)0.f };
  return v;
}

// ------------------------------------------------------------------
// Stage one 128x32 bf16 tile into LDS (global_load_lds width=16).
// ------------------------------------------------------------------
__device__ __forceinline__ void stage_tile(
    const __bf16* __restrict__ G, int ldK, int r0, int k0,
    __bf16* S, int tid, int w)
{
#pragma unroll
  for (int r = 0; r < 2; r++) {
    int ch = (r << 8) + tid;
    int row = ch >> 2;
    int col = (ch & 3) ^ ((row >> 1) & 3);
    __builtin_amdgcn_global_load_lds(
        (__attribute__((address_space(1))) uint32_t*)(G + (size_t)(r0 + row) * ldK + k0 + (col << 3)),
        (__attribute__((address_space(3))) uint32_t*)(S + (r << 11) + (w << 9)),
        16, 0, 0);
  }
}

// stage a 64x32 bf16 chunk (4KB), one 16B chunk per thread
__device__ __forceinline__ void stage64(
    const __bf16* __restrict__ W, int k0, __bf16* dst, int tid, int w)
{
  __builtin_amdgcn_global_load_lds(
      (__attribute__((address_space(1))) uint32_t*)(W + (size_t)(tid >> 2) * DIM + k0 + ((tid & 3) << 3)),
      (__attribute__((address_space(3))) uint32_t*)(dst + (w << 9)),
      16, 0, 0);
}

// ------------------------------------------------------------------
// bf16 MFMA GEMM core: acc += A[m0:+128, kbase:+nk*32] @ B[n0:+128]^T
// smem: As 2x4096 bf16 | Bs 2x4096 bf16 (32768 B)
// ------------------------------------------------------------------
__device__ __forceinline__ void gemm_core_bf16(
    char* smem, const __bf16* __restrict__ A, int ldA,
    const __bf16* __restrict__ B, int ldB,
    int m0, int n0, int kbase, int nk, v4f acc[4][4], int tid)
{
  __bf16* As = (__bf16*)smem;
  __bf16* Bs = (__bf16*)smem + 8192;
  int lane = tid & 63, w = tid >> 6;
  int wm = (w & 1) << 6, wn = (w >> 1) << 6;
  stage_tile(A, ldA, m0, kbase, As, tid, w);
  stage_tile(B, ldB, n0, kbase, Bs, tid, w);
  for (int kt = 0; kt < nk; kt++) {
    __syncthreads();
    int nxt = kt + 1;
    if (nxt < nk) {
      stage_tile(A, ldA, m0, kbase + (nxt << 5), As + ((nxt & 1) << 12), tid, w);
      stage_tile(B, ldB, n0, kbase + (nxt << 5), Bs + ((nxt & 1) << 12), tid, w);
    }
    const __bf16* Ac = As + ((kt & 1) << 12);
    const __bf16* Bc = Bs + ((kt & 1) << 12);
    int mrow = lane & 15, q = lane >> 4;
    v8bf af[4], bfr[4];
#pragma unroll
    for (int i = 0; i < 4; i++) {
      int rA = wm + (i << 4) + mrow;
      int rB = wn + (i << 4) + mrow;
      af[i]  = *(const v8bf*)(Ac + rA * 32 + ((q ^ ((rA >> 1) & 3)) << 3));
      bfr[i] = *(const v8bf*)(Bc + rB * 32 + ((q ^ ((rB >> 1) & 3)) << 3));
    }
#pragma unroll
    for (int i = 0; i < 4; i++)
#pragma unroll
      for (int j = 0; j < 4; j++)
        acc[i][j] = __builtin_amdgcn_mfma_f32_16x16x32_bf16(af[i], bfr[j], acc[i][j], 0, 0, 0);
  }
}

__device__ __forceinline__ void acc_zero(v4f acc[4][4]) {
  v4f z = {0.f, 0.f, 0.f, 0.f};
#pragma unroll
  for (int i = 0; i < 4; i++)
#pragma unroll
    for (int j = 0; j < 4; j++) acc[i][j] = z;
}

__device__ __forceinline__ void epi_store_f32(
    v4f acc[4][4], float* C, int m0, int n0, int tid)
{
  int lane = tid & 63, w = tid >> 6;
  int wm = (w & 1) << 6, wn = (w >> 1) << 6;
  int quad = lane >> 4, ncol = lane & 15;
#pragma unroll
  for (int i = 0; i < 4; i++)
#pragma unroll
    for (int j = 0; j < 4; j++) {
      int row = m0 + wm + (i << 4) + (quad << 2);
      int col = n0 + wn + (j << 4) + ncol;
#pragma unroll
      for (int r = 0; r < 4; r++)
        C[(size_t)(row + r) * DIM + col] = acc[i][j][r];
    }
}

__device__ __forceinline__ void epi_relu_energy(
    v4f acc[4][4], __bf16* C, int N, int m0, int n0, int tid,
    double* ered, double* ep_slot)
{
  int lane = tid & 63, w = tid >> 6;
  int wm = (w & 1) << 6, wn = (w >> 1) << 6;
  int quad = lane >> 4, ncol = lane & 15;
  float e = 0.f;
#pragma unroll
  for (int i = 0; i < 4; i++)
#pragma unroll
    for (int j = 0; j < 4; j++) {
      int row = m0 + wm + (i << 4) + (quad << 2);
      int col = n0 + wn + (j << 4) + ncol;
#pragma unroll
      for (int r = 0; r < 4; r++) {
        float v = acc[i][j][r];
        v = v > 0.f ? v : 0.f;
        e += v * v;
        C[(size_t)(row + r) * N + col] = (__bf16)v;
      }
    }
  for (int o = 32; o; o >>= 1) e += __shfl_xor(e, o, 64);
  if (lane == 0) ered[w] = (double)e;
  __syncthreads();
  if (tid == 0)
    *ep_slot = -0.5 * ((ered[0] + ered[1]) + (ered[2] + ered[3]));
}

// ------------------------------------------------------------------
// fp8 e4m3 GEMM, energy only (trial hopfield). smem 16416 B.
// ------------------------------------------------------------------
__device__ __forceinline__ void dev_gemm_fp8(
    char* smem, const unsigned char* __restrict__ A0,
    const unsigned char* __restrict__ B0, double* __restrict__ ep,
    int my, int nx, int tid)
{
  unsigned char* As = (unsigned char*)smem;
  unsigned char* Bs = (unsigned char*)smem + 8192;
  double* ered = (double*)(smem + 16384);
  int lane = tid & 63, w = tid >> 6;
  int wm = (w & 1) << 6, wn = (w >> 1) << 6;
  int m0 = my * 128, n0 = nx * 128;

  v4f acc[4][4];
  acc_zero(acc);

  int srow = tid >> 1;
  int sc16 = (tid & 1) ^ ((srow >> 2) & 1);
  const int nk = DIM >> 5;   // 24
#define STAGE8(buf, k0)                                                          \
  do {                                                                           \
    __builtin_amdgcn_global_load_lds(                                            \
        (__attribute__((address_space(1))) uint32_t*)(A0 + (size_t)(m0 + srow) * DIM + (k0) + (sc16 << 4)), \
        (__attribute__((address_space(3))) uint32_t*)(As + ((buf) << 12) + (w << 10)), 16, 0, 0); \
    __builtin_amdgcn_global_load_lds(                                            \
        (__attribute__((address_space(1))) uint32_t*)(B0 + (size_t)(n0 + srow) * DIM + (k0) + (sc16 << 4)), \
        (__attribute__((address_space(3))) uint32_t*)(Bs + ((buf) << 12) + (w << 10)), 16, 0, 0); \
  } while (0)

  STAGE8(0, 0);
  for (int kt = 0; kt < nk; kt++) {
    __syncthreads();
    int nxt = kt + 1;
    if (nxt < nk) STAGE8(nxt & 1, nxt << 5);
    const unsigned char* Ac = As + ((kt & 1) << 12);
    const unsigned char* Bc = Bs + ((kt & 1) << 12);
    int mrow = lane & 15, q = lane >> 4;
    long af[4], bfr[4];
#pragma unroll
    for (int i = 0; i < 4; i++) {
      int rA = wm + (i << 4) + mrow;
      int rB = wn + (i << 4) + mrow;
      int qa = q ^ (((rA >> 2) & 1) << 1);
      int qb = q ^ (((rB >> 2) & 1) << 1);
      af[i]  = *(const long*)(Ac + rA * 32 + (qa << 3));
      bfr[i] = *(const long*)(Bc + rB * 32 + (qb << 3));
    }
#pragma unroll
    for (int i = 0; i < 4; i++)
#pragma unroll
      for (int j = 0; j < 4; j++)
        acc[i][j] = __builtin_amdgcn_mfma_f32_16x16x32_fp8_fp8(af[i], bfr[j], acc[i][j], 0, 0, 0);
  }
#undef STAGE8

  float e = 0.f;
#pragma unroll
  for (int i = 0; i < 4; i++)
#pragma unroll
    for (int j = 0; j < 4; j++)
#pragma unroll
      for (int r = 0; r < 4; r++) {
        float v = acc[i][j][r];
        v = v > 0.f ? v : 0.f;
        e += v * v;
      }
  for (int o = 32; o; o >>= 1) e += __shfl_xor(e, o, 64);
  if (lane == 0) ered[w] = (double)e;
  __syncthreads();
  if (tid == 0) {
    double tot = (ered[0] + ered[1]) + (ered[2] + ered[3]);
    int tt = my / 13, ry = my - tt * 13;
    ep[EP_HOPT + tt * 312 + ry * 24 + nx] = (-0.5 / 256.0) * tot;
  }
}

// ------------------------------------------------------------------
// Build K_h, Q_h [208x64] into LDS (Ks/Qs, stride 72) via MFMA:
// K = g_rows @ Wk_h^T, Q = g_rows @ Wq_h^T.  g rows >=196 masked to 0.
// Wk/Wq are the 64-row head slabs. B-chunks double-buffered in LDS.
// ------------------------------------------------------------------
__device__ __forceinline__ void dev_build_attn_kq(
    char* smem, const __bf16* __restrict__ gsrc,
    const __bf16* __restrict__ Wk, const __bf16* __restrict__ Wq, int tid)
{
  __bf16* Ks = (__bf16*)smem;
  __bf16* Qs = (__bf16*)(smem + OFF_QS);
  __bf16* Bk = (__bf16*)(smem + OFF_BK);   // [2][2048]
  __bf16* Bq = (__bf16*)(smem + OFF_BQ);   // [2][2048]
  int lane = tid & 63, w = tid >> 6;
  int mrow = lane & 15, quad = lane >> 4;
  int ksel = quad << 3;
  v4f accK[4][4], accQ[4][4];
  acc_zero(accK);
  acc_zero(accQ);
  stage64(Wk, 0, Bk, tid, w);
  stage64(Wq, 0, Bq, tid, w);
  for (int kt = 0; kt < 24; kt++) {
    __syncthreads();
    int nxt = kt + 1;
    if (nxt < 24) {
      stage64(Wk, nxt << 5, Bk + ((nxt & 1) << 11), tid, w);
      stage64(Wq, nxt << 5, Bq + ((nxt & 1) << 11), tid, w);
    }
    const __bf16* bkc = Bk + ((kt & 1) << 11);
    const __bf16* bqc = Bq + ((kt & 1) << 11);
    v8bf bk[4], bq[4];
#pragma unroll
    for (int nt = 0; nt < 4; nt++) {
      bk[nt] = *(const v8bf*)(bkc + ((nt << 4) + mrow) * 32 + ksel);
      bq[nt] = *(const v8bf*)(bqc + ((nt << 4) + mrow) * 32 + ksel);
    }
    int koff = (kt << 5) + ksel;
#pragma unroll
    for (int mi = 0; mi < 4; mi++) {
      int mt = w + (mi << 2);
      if (mt <= 12) {
        int row = (mt << 4) + mrow;
        v8bf af = (row < SEQ) ? *(const v8bf*)(gsrc + (size_t)row * DIM + koff) : zero8();
#pragma unroll
        for (int nt = 0; nt < 4; nt++) {
          accK[mi][nt] = __builtin_amdgcn_mfma_f32_16x16x32_bf16(af, bk[nt], accK[mi][nt], 0, 0, 0);
          accQ[mi][nt] = __builtin_amdgcn_mfma_f32_16x16x32_bf16(af, bq[nt], accQ[mi][nt], 0, 0, 0);
        }
      }
    }
  }
  __syncthreads();   // all B-buffer reads done before Ks/Qs writes overlap region? (distinct, but keep ordering)
#pragma unroll
  for (int mi = 0; mi < 4; mi++) {
    int mt = w + (mi << 2);
    if (mt <= 12) {
#pragma unroll
      for (int nt = 0; nt < 4; nt++)
#pragma unroll
        for (int r = 0; r < 4; r++) {
          int row = (mt << 4) + (quad << 2) + r;
          Ks[row * 72 + (nt << 4) + mrow] = (__bf16)accK[mi][nt][r];
          Qs[row * 72 + (nt << 4) + mrow] = (__bf16)accQ[mi][nt][r];
        }
    }
  }
  __syncthreads();
}

// store K/Q LDS -> global (base path; Kb/Qb pre-offset to (b*SEQ)*DIM+h*YD)
__device__ __forceinline__ void dev_store_kq(
    char* smem, __bf16* __restrict__ Kb, __bf16* __restrict__ Qb, int tid)
{
  __bf16* Ks = (__bf16*)smem;
  __bf16* Qs = (__bf16*)(smem + OFF_QS);
  for (int i = tid; i < SEQ * 8; i += 256) {
    int row = i >> 3, c = (i & 7) << 3;
    *(v8bf*)(Kb + (size_t)row * DIM + c) = *(const v8bf*)(Ks + row * 72 + c);
    *(v8bf*)(Qb + (size_t)row * DIM + c) = *(const v8bf*)(Qs + row * 72 + c);
  }
}

// ------------------------------------------------------------------
// Attention core on prefilled Ks/Qs. SP=1: store P + energy.
// ------------------------------------------------------------------
template <int SP>
__device__ __forceinline__ void dev_attn_core(
    char* smem, __bf16* __restrict__ P, size_t Pbase,
    double* __restrict__ ep_slot, int tid)
{
  __bf16* Ks = (__bf16*)smem;
  __bf16* Qs = (__bf16*)(smem + OFF_QS);
  double* er = (double*)(smem + OFF_ER);
  int lane = tid & 63, w = tid >> 6;
  int mrow = lane & 15, quad = lane >> 4, ncol = mrow;
  int ksel = quad * 8;
  v4f zero = {0.f, 0.f, 0.f, 0.f};
  double eacc = 0.0;

  for (int mt = w; mt < 13; mt += 4) {
    int m0 = mt * 16;
    v8bf af0 = *(const v8bf*)(Qs + (m0 + mrow) * 72 + ksel);
    v8bf af1 = *(const v8bf*)(Qs + (m0 + mrow) * 72 + 32 + ksel);
    v4f acc[13];
#pragma unroll
    for (int j = 0; j < 13; j++) {
      v8bf bf0 = *(const v8bf*)(Ks + (j * 16 + mrow) * 72 + ksel);
      v8bf bf1 = *(const v8bf*)(Ks + (j * 16 + mrow) * 72 + 32 + ksel);
      v4f t = __builtin_amdgcn_mfma_f32_16x16x32_bf16(af0, bf0, zero, 0, 0, 0);
      acc[j] = __builtin_amdgcn_mfma_f32_16x16x32_bf16(af1, bf1, t, 0, 0, 0);
    }
    float mx[4] = {-1e30f, -1e30f, -1e30f, -1e30f};
#pragma unroll
    for (int j = 0; j < 13; j++) {
      bool colv = (j < 12) || (ncol < 4);
#pragma unroll
      for (int r = 0; r < 4; r++) {
        float sv = colv ? BETA_F * acc[j][r] : -1e30f;
        acc[j][r] = sv;
        mx[r] = fmaxf(mx[r], sv);
      }
    }
#pragma unroll
    for (int o = 1; o < 16; o <<= 1)
#pragma unroll
      for (int r = 0; r < 4; r++) mx[r] = fmaxf(mx[r], __shfl_xor(mx[r], o, 64));
    float zr[4] = {0.f, 0.f, 0.f, 0.f};
#pragma unroll
    for (int j = 0; j < 13; j++)
#pragma unroll
      for (int r = 0; r < 4; r++) {
        float t = (acc[j][r] > -1e29f) ? expf(acc[j][r] - mx[r]) : 0.f;
        acc[j][r] = t;
        zr[r] += t;
      }
#pragma unroll
    for (int o = 1; o < 16; o <<= 1)
#pragma unroll
      for (int r = 0; r < 4; r++) zr[r] += __shfl_xor(zr[r], o, 64);
    if (ncol == 0) {
#pragma unroll
      for (int r = 0; r < 4; r++) {
        int q = m0 + quad * 4 + r;
        if (q < SEQ) eacc += (double)(mx[r] + logf(zr[r]));
      }
    }
    if (SP) {
      float inv[4];
#pragma unroll
      for (int r = 0; r < 4; r++) inv[r] = 1.f / zr[r];
      size_t Pb = Pbase + (size_t)(m0 + quad * 4) * PCOLS;
#pragma unroll
      for (int j = 0; j < 13; j++)
#pragma unroll
        for (int r = 0; r < 4; r++) {
          int q = m0 + quad * 4 + r;
          float pv = (q < SEQ) ? acc[j][r] * inv[r] : 0.f;
          P[Pb + (size_t)r * PCOLS + j * 16 + ncol] = (__bf16)pv;
        }
#pragma unroll
      for (int r = 0; r < 4; r++)
        P[Pb + (size_t)r * PCOLS + 208 + ncol] = (__bf16)0.f;
    }
  }
  for (int o = 32; o; o >>= 1) eacc += __shfl_xor(eacc, o, 64);
  if (lane == 0) er[w] = eacc;
  __syncthreads();
  if (tid == 0)
    *ep_slot = -(double)INV_BETA * ((er[0] + er[1]) + (er[2] + er[3]));
}

// ------------------------------------------------------------------
// MFMA attention backward one side. smem: BT 29696 B.
// z=0: dQ = -(P@K); z=1: dK = -(PT@Q)
// ------------------------------------------------------------------
__device__ __forceinline__ void dev_attn_bwd(
    char* smem, const __bf16* __restrict__ Kb, const __bf16* __restrict__ Qb,
    const __bf16* __restrict__ Pg, const __bf16* __restrict__ PTg,
    __bf16* __restrict__ dQg, __bf16* __restrict__ dKg,
    int bh, int z, int tid)
{
  __bf16* BT = (__bf16*)smem;   // 64 x 232
  int b = bh / HN, h = bh - b * HN;
  const __bf16* Bsrc = (z ? Qb : Kb) + (size_t)(b * SEQ) * DIM + h * YD;
  const __bf16* Asrc = (z ? PTg : Pg) + (size_t)bh * PAREA;
  __bf16* Dst = (z ? dKg : dQg) + (size_t)(b * SEQ) * DIM + h * YD;
  for (int i = tid; i < 64 * 232 / 8; i += 256) ((v8bf*)BT)[i] = zero8();
  __syncthreads();
  for (int i = tid; i < SEQ * 8; i += 256) {
    int k = i >> 3, c = i & 7;
    v8bf v = *(const v8bf*)(Bsrc + (size_t)k * DIM + c * 8);
#pragma unroll
    for (int e = 0; e < 8; e++) BT[(c * 8 + e) * 232 + k] = v[e];
  }
  __syncthreads();

  int lane = tid & 63, w = tid >> 6;
  int mrow = lane & 15, quad = lane >> 4, ncol = mrow;
  int ksel = quad * 8;
  for (int mt = w; mt < 13; mt += 4) {
    int m0 = mt * 16;
    v4f acc[4];
    v4f zero = {0.f, 0.f, 0.f, 0.f};
#pragma unroll
    for (int n = 0; n < 4; n++) acc[n] = zero;
#pragma unroll
    for (int s = 0; s < 7; s++) {
      v8bf af = *(const v8bf*)(Asrc + (size_t)(m0 + mrow) * PCOLS + s * 32 + ksel);
#pragma unroll
      for (int n = 0; n < 4; n++) {
        v8bf bf = *(const v8bf*)(BT + (n * 16 + mrow) * 232 + s * 32 + ksel);
        acc[n] = __builtin_amdgcn_mfma_f32_16x16x32_bf16(af, bf, acc[n], 0, 0, 0);
      }
    }
    int row = m0 + quad * 4;
#pragma unroll
    for (int n = 0; n < 4; n++)
#pragma unroll
      for (int r = 0; r < 4; r++)
        if (row + r < SEQ)
          Dst[(size_t)(row + r) * DIM + n * 16 + ncol] = (__bf16)(-acc[n][r]);
  }
}

// ==================================================================
// Dispatch 1: prep = ln_fwd(1568) | cvtall(3456) | cvtT(3456) | init(288)
// ==================================================================
__global__ __launch_bounds__(256) void prep_k(
    const float* __restrict__ x, const float* __restrict__ gamma,
    const float* __restrict__ delta, const float* __restrict__ wk,
    const float* __restrict__ wq, const float* __restrict__ xi,
    __bf16* __restrict__ g, float* __restrict__ xhat, float* __restrict__ rstd,
    __bf16* __restrict__ wk_bf, __bf16* __restrict__ wq_bf,
    __bf16* __restrict__ xi_bf, int* __restrict__ xi8,
    __bf16* __restrict__ wkT, __bf16* __restrict__ wqT, __bf16* __restrict__ xiT,
    __bf16* __restrict__ gt, unsigned char* __restrict__ g8,
    __bf16* __restrict__ dq, __bf16* __restrict__ dk)
{
  __shared__ float s[4];
  __shared__ float tt[32][33];
  int blk = blockIdx.x, tid = threadIdx.x;
  if (blk < 1568) {
    int tok = blk;
    const float* xp = x + (size_t)tok * DIM;
    float v0 = xp[tid], v1 = xp[tid + 256], v2 = xp[tid + 512];
    float sum = v0 + v1 + v2;
    for (int o = 32; o; o >>= 1) sum += __shfl_xor(sum, o, 64);
    if ((tid & 63) == 0) s[tid >> 6] = sum;
    __syncthreads();
    float mu = (s[0] + s[1] + s[2] + s[3]) * (1.0f / DIM);
    __syncthreads();
    float d0 = v0 - mu, d1 = v1 - mu, d2 = v2 - mu;
    float sq = d0 * d0 + d1 * d1 + d2 * d2;
    for (int o = 32; o; o >>= 1) sq += __shfl_xor(sq, o, 64);
    if ((tid & 63) == 0) s[tid >> 6] = sq;
    __syncthreads();
    float var = (s[0] + s[1] + s[2] + s[3]) * (1.0f / DIM);
    float r = rsqrtf(var + LN_EPS_F);
    float xh0 = d0 * r, xh1 = d1 * r, xh2 = d2 * r;
    size_t base = (size_t)tok * DIM;
    g[base + tid]       = (__bf16)(gamma[tid] * xh0 + delta[tid]);
    g[base + tid + 256] = (__bf16)(gamma[tid + 256] * xh1 + delta[tid + 256]);
    g[base + tid + 512] = (__bf16)(gamma[tid + 512] * xh2 + delta[tid + 512]);
    xhat[base + tid] = xh0; xhat[base + tid + 256] = xh1; xhat[base + tid + 512] = xh2;
    if (tid == 0) rstd[tok] = r;
  } else if (blk < 5024) {
    const int W4 = DIM * DIM / 4;
    const int X4 = MXI * DIM / 4;
    int i = (blk - 1568) * 256 + tid;
    if (i < W4) {
      float4 v = ((const float4*)wk)[i];
      v4bf o = { (__bf16)v.x, (__bf16)v.y, (__bf16)v.z, (__bf16)v.w };
      *(v4bf*)(wk_bf + 4 * (size_t)i) = o;
    } else if (i < 2 * W4) {
      int j = i - W4;
      float4 v = ((const float4*)wq)[j];
      v4bf o = { (__bf16)v.x, (__bf16)v.y, (__bf16)v.z, (__bf16)v.w };
      *(v4bf*)(wq_bf + 4 * (size_t)j) = o;
    } else if (i < 2 * W4 + X4) {
      int j = i - 2 * W4;
      float4 v = ((const float4*)xi)[j];
      v4bf o = { (__bf16)v.x, (__bf16)v.y, (__bf16)v.z, (__bf16)v.w };
      *(v4bf*)(xi_bf + 4 * (size_t)j) = o;
      int pk = __builtin_amdgcn_cvt_pk_fp8_f32(16.f * v.x, 16.f * v.y, 0, false);
      pk = __builtin_amdgcn_cvt_pk_fp8_f32(16.f * v.z, 16.f * v.w, pk, true);
      xi8[j] = pk;
    }
  } else if (blk < 8480) {
    int job = blk - 5024;
    const float* src; __bf16* dst; int R; float scale; int r0, c0;
    if (job < 576)       { src = wk; dst = wkT; R = DIM; scale = 1.f;  int j = job;        c0 = (j % 24) * 32; r0 = (j / 24) * 32; }
    else if (job < 1152) { src = wq; dst = wqT; R = DIM; scale = 1.f;  int j = job - 576;  c0 = (j % 24) * 32; r0 = (j / 24) * 32; }
    else                 { src = xi; dst = xiT; R = MXI; scale = -1.f; int j = job - 1152; c0 = (j % 24) * 32; r0 = (j / 24) * 32; }
    int tx = tid & 31, ty = tid >> 5;
    for (int rr = ty; rr < 32; rr += 8)
      tt[rr][tx] = src[(size_t)(r0 + rr) * DIM + c0 + tx];
    __syncthreads();
    for (int rr = ty; rr < 32; rr += 8)
      dst[(size_t)(c0 + rr) * R + r0 + tx] = (__bf16)(scale * tt[tx][rr]);
  } else {
    int i = (blk - 8480) * 256 + tid;
    const int PADN = (MPAD - TOK) * DIM;   // 73728
    if (i < PADN) {
      size_t o = (size_t)TOK * DIM + i;
      g[o] = (__bf16)0.f; dq[o] = (__bf16)0.f; dk[o] = (__bf16)0.f;
#pragma unroll
      for (int t = 0; t < 4; t++) {
        gt[(size_t)t * MPAD * DIM + o] = (__bf16)0.f;
        g8[(size_t)t * MPAD * DIM + o] = 0;
      }
    }
  }
}

// ==================================================================
// Dispatch 2: fwd = fused base attn (96: build K/Q, store Kb/Qb/P,
// energy) | hop base GEMM (312). grid 408.
// ==================================================================
__global__ __launch_bounds__(256, 2) void fwd_k(
    const __bf16* __restrict__ g, const __bf16* __restrict__ wk_bf,
    const __bf16* __restrict__ wq_bf, const __bf16* __restrict__ xi_bf,
    __bf16* __restrict__ Kb, __bf16* __restrict__ Qb, __bf16* __restrict__ P,
    __bf16* __restrict__ rh, double* __restrict__ ep)
{
  __shared__ __align__(16) char smem[SM_ATTN];
  int blk = blockIdx.x, tid = threadIdx.x;
  if (blk < 96) {
    int bh = blk, b = bh / HN, h = bh - b * HN;
    const __bf16* gsrc = g + (size_t)(b * SEQ) * DIM;
    dev_build_attn_kq(smem, gsrc, wk_bf + (size_t)h * YD * DIM,
                      wq_bf + (size_t)h * YD * DIM, tid);
    dev_store_kq(smem, Kb + (size_t)(b * SEQ) * DIM + h * YD,
                 Qb + (size_t)(b * SEQ) * DIM + h * YD, tid);
    dev_attn_core<1>(smem, P, (size_t)bh * PAREA, ep + bh, tid);
  } else {
    int j = blk - 96;
    int ry = j / 24, nx = j - ry * 24;
    v4f acc[4][4];
    acc_zero(acc);
    gemm_core_bf16(smem, g, DIM, xi_bf, DIM, ry * 128, nx * 128, 0, 24, acc, tid);
    epi_relu_energy(acc, rh, MXI, ry * 128, nx * 128, tid,
                    (double*)(smem + OFF_ER), ep + EP_HOPB + ry * 24 + nx);
  }
}

// ==================================================================
// Dispatch 3: P -> PT transpose. grid (96, 7, 7).
// ==================================================================
__global__ __launch_bounds__(256) void ptrans_k(
    const __bf16* __restrict__ Pg, __bf16* __restrict__ PTg)
{
  __shared__ __bf16 t[32][33];
  int bh = blockIdx.x;
  int q0 = blockIdx.y * 32, k0 = blockIdx.z * 32;
  int tx = threadIdx.x & 31, ty = threadIdx.x >> 5;
  const __bf16* Pb = Pg + (size_t)bh * PAREA;
  __bf16* PTb = PTg + (size_t)bh * PAREA;
  for (int rr = ty; rr < 32; rr += 8)
    t[rr][tx] = (q0 + rr < PROWS) ? Pb[(size_t)(q0 + rr) * PCOLS + k0 + tx] : (__bf16)0.f;
  __syncthreads();
  for (int rr = ty; rr < 32; rr += 8)
    if (k0 + rr < PROWS)
      PTb[(size_t)(k0 + rr) * PCOLS + q0 + tx] = t[tx][rr];
}

// ==================================================================
// Dispatch 4: bwdA = attn_bwd z0 (96) | z1 (96) | rh@xiT quarters (312).
// grid 504.
// ==================================================================
__global__ __launch_bounds__(256, 4) void bwdA_k(
    const __bf16* __restrict__ Kb, const __bf16* __restrict__ Qb,
    const __bf16* __restrict__ P, const __bf16* __restrict__ PT,
    __bf16* __restrict__ dQg, __bf16* __restrict__ dKg,
    const __bf16* __restrict__ rh, const __bf16* __restrict__ xiT,
    float* __restrict__ dGp)
{
  __shared__ __align__(16) char smem[32768];
  int blk = blockIdx.x, tid = threadIdx.x;
  if (blk < 192) {
    int z = blk / 96, bh = blk - z * 96;
    dev_attn_bwd(smem, Kb, Qb, P, PT, dQg, dKg, bh, z, tid);
  } else {
    int j = blk - 192;          // 0..311
    int qd = j / 78, jj = j - qd * 78;
    int my = jj / 6, nx = jj - my * 6;
    v4f acc[4][4];
    acc_zero(acc);
    gemm_core_bf16(smem, rh, MXI, xiT, MXI, my * 128, nx * 128, qd * 768, 24, acc, tid);
    epi_store_f32(acc, dGp + (size_t)qd * NPE, my * 128, nx * 128, tid);
  }
}

// ==================================================================
// Dispatch 5: bwdB = dQg@wqT halves | dKg@wkT halves. grid 312.
// ==================================================================
__global__ __launch_bounds__(256, 4) void bwdB_k(
    const __bf16* __restrict__ dQg, const __bf16* __restrict__ wqT,
    const __bf16* __restrict__ dKg, const __bf16* __restrict__ wkT,
    float* __restrict__ dGp)
{
  __shared__ __align__(16) char smem[32768];
  int blk = blockIdx.x, tid = threadIdx.x;
  int z = blk / 156, jj = blk - z * 156;
  int half = jj / 78, j2 = jj - half * 78;
  int my = j2 / 6, nx = j2 - my * 6;
  const __bf16* A = z ? dKg : dQg;
  const __bf16* B = z ? wkT : wqT;
  v4f acc[4][4];
  acc_zero(acc);
  gemm_core_bf16(smem, A, DIM, B, DIM, my * 128, nx * 128, half * 384, 12, acc, tid);
  epi_store_f32(acc, dGp + (size_t)(4 + z * 2 + half) * NPE, my * 128, nx * 128, tid);
}

// ==================================================================
// Dispatch 6: fused LN-backward (sum 8 partials) + trial axpy+LN. grid 1568.
// ==================================================================
__global__ __launch_bounds__(256) void lnbwd_axpy_k(
    const float* __restrict__ dGp,
    const float* __restrict__ xhat, const float* __restrict__ rstd,
    const float* __restrict__ gamma, const float* __restrict__ delta,
    const float* __restrict__ x, float* __restrict__ grad,
    __bf16* __restrict__ gt, unsigned char* __restrict__ g8)
{
  __shared__ float s[8];
  int tok = blockIdx.x, tid = threadIdx.x;
  size_t base = (size_t)tok * DIM;
  float ga0 = gamma[tid], ga1 = gamma[tid + 256], ga2 = gamma[tid + 512];
  float de0 = delta[tid], de1 = delta[tid + 256], de2 = delta[tid + 512];
  float g0 = 0.f, g1 = 0.f, g2 = 0.f;
#pragma unroll
  for (int pi = 0; pi < 8; pi++) {
    const float* p = dGp + (size_t)pi * NPE;
    g0 += p[base + tid];
    g1 += p[base + tid + 256];
    g2 += p[base + tid + 512];
  }
  float dh0 = g0 * ga0, dh1 = g1 * ga1, dh2 = g2 * ga2;
  float xh0 = xhat[base + tid], xh1 = xhat[base + tid + 256], xh2 = xhat[base + tid + 512];
  float s1 = dh0 + dh1 + dh2;
  float s2 = dh0 * xh0 + dh1 * xh1 + dh2 * xh2;
  for (int o = 32; o; o >>= 1) { s1 += __shfl_xor(s1, o, 64); s2 += __shfl_xor(s2, o, 64); }
  if ((tid & 63) == 0) { s[tid >> 6] = s1; s[4 + (tid >> 6)] = s2; }
  __syncthreads();
  float m1 = (s[0] + s[1] + s[2] + s[3]) * (1.0f / DIM);
  float m2 = (s[4] + s[5] + s[6] + s[7]) * (1.0f / DIM);
  float r = rstd[tok];
  float gr0 = r * (dh0 - m1 - xh0 * m2);
  float gr1 = r * (dh1 - m1 - xh1 * m2);
  float gr2 = r * (dh2 - m1 - xh2 * m2);
  grad[base + tid] = gr0; grad[base + tid + 256] = gr1; grad[base + tid + 512] = gr2;
  float xv0 = x[base + tid], xv1 = x[base + tid + 256], xv2 = x[base + tid + 512];
#pragma unroll
  for (int t = 0; t < 4; t++) {
    float lr = 1.0f / (float)(1 << t);
    float v0 = xv0 - lr * gr0, v1 = xv1 - lr * gr1, v2 = xv2 - lr * gr2;
    float sum = v0 + v1 + v2;
    for (int o = 32; o; o >>= 1) sum += __shfl_xor(sum, o, 64);
    __syncthreads();
    if ((tid & 63) == 0) s[tid >> 6] = sum;
    __syncthreads();
    float mu = (s[0] + s[1] + s[2] + s[3]) * (1.0f / DIM);
    float d0 = v0 - mu, d1 = v1 - mu, d2 = v2 - mu;
    float sq = d0 * d0 + d1 * d1 + d2 * d2;
    for (int o = 32; o; o >>= 1) sq += __shfl_xor(sq, o, 64);
    __syncthreads();
    if ((tid & 63) == 0) s[tid >> 6] = sq;
    __syncthreads();
    float var = (s[0] + s[1] + s[2] + s[3]) * (1.0f / DIM);
    float r2 = rsqrtf(var + LN_EPS_F);
    float o0 = ga0 * (d0 * r2) + de0;
    float o1 = ga1 * (d1 * r2) + de1;
    float o2 = ga2 * (d2 * r2) + de2;
    size_t ob = ((size_t)t * MPAD + tok) * DIM;
    gt[ob + tid] = (__bf16)o0; gt[ob + tid + 256] = (__bf16)o1; gt[ob + tid + 512] = (__bf16)o2;
    g8[ob + tid]       = (unsigned char)(__builtin_amdgcn_cvt_pk_fp8_f32(o0, o0, 0, false) & 0xff);
    g8[ob + tid + 256] = (unsigned char)(__builtin_amdgcn_cvt_pk_fp8_f32(o1, o1, 0, false) & 0xff);
    g8[ob + tid + 512] = (unsigned char)(__builtin_amdgcn_cvt_pk_fp8_f32(o2, o2, 0, false) & 0xff);
  }
}

// ==================================================================
// Dispatch 7: fp8 trial hopfield, 624 blocks x 2 jobs (no tail).
// ==================================================================
__global__ __launch_bounds__(256, 4) void hop8_k(
    const unsigned char* __restrict__ g8, const unsigned char* __restrict__ xi8,
    double* __restrict__ ep)
{
  __shared__ __align__(16) char smem[16416];
  int tid = threadIdx.x;
#pragma unroll
  for (int jj = 0; jj < 2; jj++) {
    int id = blockIdx.x + jj * 624;
    __syncthreads();
    int my = id / 24, nx = id - my * 24;
    dev_gemm_fp8(smem, g8, xi8, ep, my, nx, tid);
  }
}

// ==================================================================
// Dispatch 8: fused trial attention (build K/Q on the fly). grid (96,4).
// ==================================================================
__global__ __launch_bounds__(256, 2) void tattn_k(
    const __bf16* __restrict__ gt, const __bf16* __restrict__ wk_bf,
    const __bf16* __restrict__ wq_bf, double* __restrict__ ep)
{
  __shared__ __align__(16) char smem[SM_ATTN];
  int bh = blockIdx.x, t = blockIdx.y, tid = threadIdx.x;
  int b = bh / HN, h = bh - b * HN;
  const __bf16* gsrc = gt + ((size_t)t * MPAD + b * SEQ) * DIM;
  dev_build_attn_kq(smem, gsrc, wk_bf + (size_t)h * YD * DIM,
                    wq_bf + (size_t)h * YD * DIM, tid);
  dev_attn_core<0>(smem, (__bf16*)nullptr, 0, ep + (t + 1) * 96 + bh, tid);
}

// ==================================================================
// Dispatch 9: fused reduce+choose+update. grid 624 (grid-stride).
// ==================================================================
__global__ __launch_bounds__(256) void update_k(
    const float* __restrict__ x, const float* __restrict__ grad,
    const double* __restrict__ ep, float* __restrict__ out, int n4)
{
  __shared__ double sm[4];
  __shared__ float chs;
  int tid = threadIdx.x;
  double e[5];
  for (int s = 0; s < 5; s++) {
    double acc = 0.0;
    int a0 = 96 * s;
    for (int i = tid; i < 96; i += 256) acc += ep[a0 + i];
    int b0 = (s == 0) ? EP_HOPB : EP_HOPT + 312 * (s - 1);
    for (int i = tid; i < 312; i += 256) acc += ep[b0 + i];
    for (int o = 32; o; o >>= 1) acc += __shfl_xor(acc, o, 64);
    if ((tid & 63) == 0) sm[tid >> 6] = acc;
    __syncthreads();
    e[s] = (sm[0] + sm[1]) + (sm[2] + sm[3]);
    __syncthreads();
  }
  if (tid == 0) {
    double e0 = e[0];
    float c = 0.0625f;
    if (e[4] < e0) c = 0.125f;
    if (e[3] < e0) c = 0.25f;
    if (e[2] < e0) c = 0.5f;
    if (e[1] < e0) c = 1.0f;
    chs = c;
  }
  __syncthreads();
  float lr = chs;
  for (int i = blockIdx.x * 256 + tid; i < n4; i += gridDim.x * 256) {
    const float4 xv = ((const float4*)x)[i];
    const float4 gv = ((const float4*)grad)[i];
    float4 o;
    o.x = xv.x - lr * gv.x; o.y = xv.y - lr * gv.y;
    o.z = xv.z - lr * gv.z; o.w = xv.w - lr * gv.w;
    ((float4*)out)[i] = o;
  }
}

// ------------------------------------------------------------------
extern "C" void kernel_launch(void* const* d_in, const int* in_sizes, int n_in,
                              void* d_out, int out_size, void* d_ws, size_t ws_size,
                              hipStream_t stream)
{
  const float* x     = (const float*)d_in[0];
  const float* gamma = (const float*)d_in[1];
  const float* delta = (const float*)d_in[2];
  const float* wk    = (const float*)d_in[3];
  const float* wq    = (const float*)d_in[4];
  const float* xi    = (const float*)d_in[5];
  float* out = (float*)d_out;

  const size_t NE = (size_t)TOK * DIM;
  const size_t NP = NPE;

  double* eparts = (double*)d_ws;                // 2040 doubles
  float* fp = (float*)(eparts + EP_TOTAL + 8);
  float* xhat = fp;  fp += NE;
  float* grad = fp;  fp += NE;
  float* rstd = fp;  fp += TOK;
  fp += 16;
  float* dGp = (float*)(((uintptr_t)fp + 15) & ~(uintptr_t)15);   // 8 * NP floats
  __bf16* bp = (__bf16*)(dGp + 8 * NP);
  __bf16* g_bf   = bp;  bp += NP;
  __bf16* g_tr   = bp;  bp += 4 * NP;
  __bf16* Kb_bf  = bp;  bp += NP;
  __bf16* Qb_bf  = bp;  bp += NP;
  __bf16* dQg_bf = bp;  bp += NP;
  __bf16* dKg_bf = bp;  bp += NP;
  __bf16* rh_bf  = bp;  bp += (size_t)MPAD * MXI;
  __bf16* wk_bf  = bp;  bp += (size_t)DIM * DIM;
  __bf16* wq_bf  = bp;  bp += (size_t)DIM * DIM;
  __bf16* wkT_bf = bp;  bp += (size_t)DIM * DIM;
  __bf16* wqT_bf = bp;  bp += (size_t)DIM * DIM;
  __bf16* xi_bf  = bp;  bp += (size_t)MXI * DIM;
  __bf16* xiT_bf = bp;  bp += (size_t)DIM * MXI;
  __bf16* P_bf   = bp;  bp += (size_t)96 * PAREA;
  __bf16* PT_bf  = bp;  bp += (size_t)96 * PAREA;
  unsigned char* g8  = (unsigned char*)bp;  bp += 2 * NP;              // 4*NP bytes
  unsigned char* xi8 = (unsigned char*)bp;  bp += (size_t)MXI * DIM / 2;

  const int n4 = (int)(NE / 4);
  dim3 blk(256);

  // 1. prep
  hipLaunchKernelGGL(prep_k, dim3(8768), blk, 0, stream,
                     x, gamma, delta, wk, wq, xi,
                     g_bf, xhat, rstd, wk_bf, wq_bf, xi_bf, (int*)xi8,
                     wkT_bf, wqT_bf, xiT_bf, g_tr, g8, dQg_bf, dKg_bf);
  // 2. fused base attn + hop base
  hipLaunchKernelGGL(fwd_k, dim3(408), blk, 0, stream,
                     g_bf, wk_bf, wq_bf, xi_bf, Kb_bf, Qb_bf, P_bf, rh_bf, eparts);
  // 3. ptrans
  hipLaunchKernelGGL(ptrans_k, dim3(96, 7, 7), blk, 0, stream, P_bf, PT_bf);
  // 4. attn_bwd + rh@xiT quarters
  hipLaunchKernelGGL(bwdA_k, dim3(504), blk, 0, stream,
                     Kb_bf, Qb_bf, P_bf, PT_bf, dQg_bf, dKg_bf, rh_bf, xiT_bf, dGp);
  // 5. dQg@wqT + dKg@wkT (K-halved)
  hipLaunchKernelGGL(bwdB_k, dim3(312), blk, 0, stream,
                     dQg_bf, wqT_bf, dKg_bf, wkT_bf, dGp);
  // 6. ln_bwd + trial axpy/LN fused
  hipLaunchKernelGGL(lnbwd_axpy_k, dim3(TOK), blk, 0, stream,
                     dGp, xhat, rstd, gamma, delta, x, grad, g_tr, g8);
  // 7. fp8 trial hopfield
  hipLaunchKernelGGL(hop8_k, dim3(624), blk, 0, stream, g8, xi8, eparts);
  // 8. fused trial attention
  hipLaunchKernelGGL(tattn_k, dim3(96, 4), blk, 0, stream,
                     g_tr, wk_bf, wq_bf, eparts);
  // 9. reduce + choose + update
  hipLaunchKernelGGL(update_k, dim3(624), blk, 0, stream,
                     x, grad, eparts, out, n4);
}

// Round 10
// 277.360 us; speedup vs baseline: 1.2131x; 1.1058x over previous
//
#include <hip/hip_runtime.h>
#include <math.h>

#define TOK 1568      // B*N = 8*196
#define MPAD 1664     // 13 * 128
#define DIM 768
#define HN 12
#define SEQ 196
#define YD 64
#define MXI 3072
#define BETA_F 0.125f
#define INV_BETA 8.0f
#define LN_EPS_F 1e-5f

// P/PT padded geometry: rows 208 (13*16), cols 224 (7*32)
#define PROWS 208
#define PCOLS 224
#define PAREA (PROWS * PCOLS)

// energy partials (doubles): attn ver*96+bh, ver 0..4 -> [0,480)
// hop base [480,792) ; hop trial t*312 -> [792,2040)
#define EP_HOPB 480
#define EP_HOPT 792
#define EP_TOTAL 2040

#define NPE ((size_t)MPAD * DIM)

// fused-attn LDS layout (bytes)
#define OFF_QS 29952
#define OFF_BK 59904
#define OFF_BQ 68096
#define OFF_ER 76288
#define SM_ATTN 76352

typedef __bf16 v8bf __attribute__((ext_vector_type(8)));
typedef __bf16 v4bf __attribute__((ext_vector_type(4)));
typedef float  v4f  __attribute__((ext_vector_type(4)));

__device__ __forceinline__ v8bf zero8() {
  v8bf v = { (__bf16)0.f, (__bf16)0.f, (__bf16)0.f, (__bf16)0.f,
             (__bf16)0.f, (__bf16)0.f, (__bf16)0.f, (__bf16)0.f };
  return v;
}

// ------------------------------------------------------------------
// Stage one 128x32 bf16 tile into LDS (global_load_lds width=16).
// ------------------------------------------------------------------
__device__ __forceinline__ void stage_tile(
    const __bf16* __restrict__ G, int ldK, int r0, int k0,
    __bf16* S, int tid, int w)
{
#pragma unroll
  for (int r = 0; r < 2; r++) {
    int ch = (r << 8) + tid;
    int row = ch >> 2;
    int col = (ch & 3) ^ ((row >> 1) & 3);
    __builtin_amdgcn_global_load_lds(
        (__attribute__((address_space(1))) uint32_t*)(G + (size_t)(r0 + row) * ldK + k0 + (col << 3)),
        (__attribute__((address_space(3))) uint32_t*)(S + (r << 11) + (w << 9)),
        16, 0, 0);
  }
}

// stage a 64x32 bf16 chunk (4KB), one 16B chunk per thread
__device__ __forceinline__ void stage64(
    const __bf16* __restrict__ W, int k0, __bf16* dst, int tid, int w)
{
  __builtin_amdgcn_global_load_lds(
      (__attribute__((address_space(1))) uint32_t*)(W + (size_t)(tid >> 2) * DIM + k0 + ((tid & 3) << 3)),
      (__attribute__((address_space(3))) uint32_t*)(dst + (w << 9)),
      16, 0, 0);
}

// ------------------------------------------------------------------
// bf16 MFMA GEMM core: acc += A[m0:+128, kbase:+nk*32] @ B[n0:+128]^T
// smem: As 2x4096 bf16 | Bs 2x4096 bf16 (32768 B)
// ------------------------------------------------------------------
__device__ __forceinline__ void gemm_core_bf16(
    char* smem, const __bf16* __restrict__ A, int ldA,
    const __bf16* __restrict__ B, int ldB,
    int m0, int n0, int kbase, int nk, v4f acc[4][4], int tid)
{
  __bf16* As = (__bf16*)smem;
  __bf16* Bs = (__bf16*)smem + 8192;
  int lane = tid & 63, w = tid >> 6;
  int wm = (w & 1) << 6, wn = (w >> 1) << 6;
  stage_tile(A, ldA, m0, kbase, As, tid, w);
  stage_tile(B, ldB, n0, kbase, Bs, tid, w);
  for (int kt = 0; kt < nk; kt++) {
    __syncthreads();
    int nxt = kt + 1;
    if (nxt < nk) {
      stage_tile(A, ldA, m0, kbase + (nxt << 5), As + ((nxt & 1) << 12), tid, w);
      stage_tile(B, ldB, n0, kbase + (nxt << 5), Bs + ((nxt & 1) << 12), tid, w);
    }
    const __bf16* Ac = As + ((kt & 1) << 12);
    const __bf16* Bc = Bs + ((kt & 1) << 12);
    int mrow = lane & 15, q = lane >> 4;
    v8bf af[4], bfr[4];
#pragma unroll
    for (int i = 0; i < 4; i++) {
      int rA = wm + (i << 4) + mrow;
      int rB = wn + (i << 4) + mrow;
      af[i]  = *(const v8bf*)(Ac + rA * 32 + ((q ^ ((rA >> 1) & 3)) << 3));
      bfr[i] = *(const v8bf*)(Bc + rB * 32 + ((q ^ ((rB >> 1) & 3)) << 3));
    }
#pragma unroll
    for (int i = 0; i < 4; i++)
#pragma unroll
      for (int j = 0; j < 4; j++)
        acc[i][j] = __builtin_amdgcn_mfma_f32_16x16x32_bf16(af[i], bfr[j], acc[i][j], 0, 0, 0);
  }
}

__device__ __forceinline__ void acc_zero(v4f acc[4][4]) {
  v4f z = {0.f, 0.f, 0.f, 0.f};
#pragma unroll
  for (int i = 0; i < 4; i++)
#pragma unroll
    for (int j = 0; j < 4; j++) acc[i][j] = z;
}

__device__ __forceinline__ void epi_store_f32(
    v4f acc[4][4], float* C, int m0, int n0, int tid)
{
  int lane = tid & 63, w = tid >> 6;
  int wm = (w & 1) << 6, wn = (w >> 1) << 6;
  int quad = lane >> 4, ncol = lane & 15;
#pragma unroll
  for (int i = 0; i < 4; i++)
#pragma unroll
    for (int j = 0; j < 4; j++) {
      int row = m0 + wm + (i << 4) + (quad << 2);
      int col = n0 + wn + (j << 4) + ncol;
#pragma unroll
      for (int r = 0; r < 4; r++)
        C[(size_t)(row + r) * DIM + col] = acc[i][j][r];
    }
}

__device__ __forceinline__ void epi_relu_energy(
    v4f acc[4][4], __bf16* C, int N, int m0, int n0, int tid,
    double* ered, double* ep_slot)
{
  int lane = tid & 63, w = tid >> 6;
  int wm = (w & 1) << 6, wn = (w >> 1) << 6;
  int quad = lane >> 4, ncol = lane & 15;
  float e = 0.f;
#pragma unroll
  for (int i = 0; i < 4; i++)
#pragma unroll
    for (int j = 0; j < 4; j++) {
      int row = m0 + wm + (i << 4) + (quad << 2);
      int col = n0 + wn + (j << 4) + ncol;
#pragma unroll
      for (int r = 0; r < 4; r++) {
        float v = acc[i][j][r];
        v = v > 0.f ? v : 0.f;
        e += v * v;
        C[(size_t)(row + r) * N + col] = (__bf16)v;
      }
    }
  for (int o = 32; o; o >>= 1) e += __shfl_xor(e, o, 64);
  if (lane == 0) ered[w] = (double)e;
  __syncthreads();
  if (tid == 0)
    *ep_slot = -0.5 * ((ered[0] + ered[1]) + (ered[2] + ered[3]));
}

// ------------------------------------------------------------------
// fp8 e4m3 GEMM, energy only (trial hopfield). smem 16416 B.
// ------------------------------------------------------------------
__device__ __forceinline__ void dev_gemm_fp8(
    char* smem, const unsigned char* __restrict__ A0,
    const unsigned char* __restrict__ B0, double* __restrict__ ep,
    int my, int nx, int tid)
{
  unsigned char* As = (unsigned char*)smem;
  unsigned char* Bs = (unsigned char*)smem + 8192;
  double* ered = (double*)(smem + 16384);
  int lane = tid & 63, w = tid >> 6;
  int wm = (w & 1) << 6, wn = (w >> 1) << 6;
  int m0 = my * 128, n0 = nx * 128;

  v4f acc[4][4];
  acc_zero(acc);

  int srow = tid >> 1;
  int sc16 = (tid & 1) ^ ((srow >> 2) & 1);
  const int nk = DIM >> 5;   // 24
#define STAGE8(buf, k0)                                                          \
  do {                                                                           \
    __builtin_amdgcn_global_load_lds(                                            \
        (__attribute__((address_space(1))) uint32_t*)(A0 + (size_t)(m0 + srow) * DIM + (k0) + (sc16 << 4)), \
        (__attribute__((address_space(3))) uint32_t*)(As + ((buf) << 12) + (w << 10)), 16, 0, 0); \
    __builtin_amdgcn_global_load_lds(                                            \
        (__attribute__((address_space(1))) uint32_t*)(B0 + (size_t)(n0 + srow) * DIM + (k0) + (sc16 << 4)), \
        (__attribute__((address_space(3))) uint32_t*)(Bs + ((buf) << 12) + (w << 10)), 16, 0, 0); \
  } while (0)

  STAGE8(0, 0);
  for (int kt = 0; kt < nk; kt++) {
    __syncthreads();
    int nxt = kt + 1;
    if (nxt < nk) STAGE8(nxt & 1, nxt << 5);
    const unsigned char* Ac = As + ((kt & 1) << 12);
    const unsigned char* Bc = Bs + ((kt & 1) << 12);
    int mrow = lane & 15, q = lane >> 4;
    long af[4], bfr[4];
#pragma unroll
    for (int i = 0; i < 4; i++) {
      int rA = wm + (i << 4) + mrow;
      int rB = wn + (i << 4) + mrow;
      int qa = q ^ (((rA >> 2) & 1) << 1);
      int qb = q ^ (((rB >> 2) & 1) << 1);
      af[i]  = *(const long*)(Ac + rA * 32 + (qa << 3));
      bfr[i] = *(const long*)(Bc + rB * 32 + (qb << 3));
    }
#pragma unroll
    for (int i = 0; i < 4; i++)
#pragma unroll
      for (int j = 0; j < 4; j++)
        acc[i][j] = __builtin_amdgcn_mfma_f32_16x16x32_fp8_fp8(af[i], bfr[j], acc[i][j], 0, 0, 0);
  }
#undef STAGE8

  float e = 0.f;
#pragma unroll
  for (int i = 0; i < 4; i++)
#pragma unroll
    for (int j = 0; j < 4; j++)
#pragma unroll
      for (int r = 0; r < 4; r++) {
        float v = acc[i][j][r];
        v = v > 0.f ? v : 0.f;
        e += v * v;
      }
  for (int o = 32; o; o >>= 1) e += __shfl_xor(e, o, 64);
  if (lane == 0) ered[w] = (double)e;
  __syncthreads();
  if (tid == 0) {
    double tot = (ered[0] + ered[1]) + (ered[2] + ered[3]);
    int tt = my / 13, ry = my - tt * 13;
    ep[EP_HOPT + tt * 312 + ry * 24 + nx] = (-0.5 / 256.0) * tot;
  }
}

// ------------------------------------------------------------------
// Build K_h, Q_h [208x64] into LDS (Ks/Qs, stride 72) via MFMA:
// K = g_rows @ Wk_h^T, Q = g_rows @ Wq_h^T.  g rows >=196 masked to 0.
// A-fragments prefetched one kt ahead (direct-global, latency cover).
// ------------------------------------------------------------------
__device__ __forceinline__ void dev_build_attn_kq(
    char* smem, const __bf16* __restrict__ gsrc,
    const __bf16* __restrict__ Wk, const __bf16* __restrict__ Wq, int tid)
{
  __bf16* Ks = (__bf16*)smem;
  __bf16* Qs = (__bf16*)(smem + OFF_QS);
  __bf16* Bk = (__bf16*)(smem + OFF_BK);   // [2][2048]
  __bf16* Bq = (__bf16*)(smem + OFF_BQ);   // [2][2048]
  int lane = tid & 63, w = tid >> 6;
  int mrow = lane & 15, quad = lane >> 4;
  int ksel = quad << 3;
  v4f accK[4][4], accQ[4][4];
  acc_zero(accK);
  acc_zero(accQ);
  stage64(Wk, 0, Bk, tid, w);
  stage64(Wq, 0, Bq, tid, w);
  // prefetch A fragments for kt=0
  v8bf afc[4];
#pragma unroll
  for (int mi = 0; mi < 4; mi++) {
    int mt = w + (mi << 2);
    int row = (mt << 4) + mrow;
    afc[mi] = (mt <= 12 && row < SEQ)
                  ? *(const v8bf*)(gsrc + (size_t)row * DIM + ksel) : zero8();
  }
  for (int kt = 0; kt < 24; kt++) {
    __syncthreads();
    int nxt = kt + 1;
    if (nxt < 24) {
      stage64(Wk, nxt << 5, Bk + ((nxt & 1) << 11), tid, w);
      stage64(Wq, nxt << 5, Bq + ((nxt & 1) << 11), tid, w);
    }
    // prefetch A fragments for kt+1 (register pipeline)
    v8bf afn[4];
    if (nxt < 24) {
      int koff = (nxt << 5) + ksel;
#pragma unroll
      for (int mi = 0; mi < 4; mi++) {
        int mt = w + (mi << 2);
        int row = (mt << 4) + mrow;
        afn[mi] = (mt <= 12 && row < SEQ)
                      ? *(const v8bf*)(gsrc + (size_t)row * DIM + koff) : zero8();
      }
    } else {
#pragma unroll
      for (int mi = 0; mi < 4; mi++) afn[mi] = zero8();
    }
    const __bf16* bkc = Bk + ((kt & 1) << 11);
    const __bf16* bqc = Bq + ((kt & 1) << 11);
    v8bf bk[4], bq[4];
#pragma unroll
    for (int nt = 0; nt < 4; nt++) {
      bk[nt] = *(const v8bf*)(bkc + ((nt << 4) + mrow) * 32 + ksel);
      bq[nt] = *(const v8bf*)(bqc + ((nt << 4) + mrow) * 32 + ksel);
    }
#pragma unroll
    for (int mi = 0; mi < 4; mi++) {
      int mt = w + (mi << 2);
      if (mt <= 12) {
#pragma unroll
        for (int nt = 0; nt < 4; nt++) {
          accK[mi][nt] = __builtin_amdgcn_mfma_f32_16x16x32_bf16(afc[mi], bk[nt], accK[mi][nt], 0, 0, 0);
          accQ[mi][nt] = __builtin_amdgcn_mfma_f32_16x16x32_bf16(afc[mi], bq[nt], accQ[mi][nt], 0, 0, 0);
        }
      }
    }
#pragma unroll
    for (int mi = 0; mi < 4; mi++) afc[mi] = afn[mi];
  }
  __syncthreads();
#pragma unroll
  for (int mi = 0; mi < 4; mi++) {
    int mt = w + (mi << 2);
    if (mt <= 12) {
#pragma unroll
      for (int nt = 0; nt < 4; nt++)
#pragma unroll
        for (int r = 0; r < 4; r++) {
          int row = (mt << 4) + (quad << 2) + r;
          Ks[row * 72 + (nt << 4) + mrow] = (__bf16)accK[mi][nt][r];
          Qs[row * 72 + (nt << 4) + mrow] = (__bf16)accQ[mi][nt][r];
        }
    }
  }
  __syncthreads();
}

// store K/Q LDS -> global (base path; Kb/Qb pre-offset to (b*SEQ)*DIM+h*YD)
__device__ __forceinline__ void dev_store_kq(
    char* smem, __bf16* __restrict__ Kb, __bf16* __restrict__ Qb, int tid)
{
  __bf16* Ks = (__bf16*)smem;
  __bf16* Qs = (__bf16*)(smem + OFF_QS);
  for (int i = tid; i < SEQ * 8; i += 256) {
    int row = i >> 3, c = (i & 7) << 3;
    *(v8bf*)(Kb + (size_t)row * DIM + c) = *(const v8bf*)(Ks + row * 72 + c);
    *(v8bf*)(Qb + (size_t)row * DIM + c) = *(const v8bf*)(Qs + row * 72 + c);
  }
}

// ------------------------------------------------------------------
// Attention core on prefilled Ks/Qs. SP=1: store P + energy.
// ------------------------------------------------------------------
template <int SP>
__device__ __forceinline__ void dev_attn_core(
    char* smem, __bf16* __restrict__ P, size_t Pbase,
    double* __restrict__ ep_slot, int tid)
{
  __bf16* Ks = (__bf16*)smem;
  __bf16* Qs = (__bf16*)(smem + OFF_QS);
  double* er = (double*)(smem + OFF_ER);
  int lane = tid & 63, w = tid >> 6;
  int mrow = lane & 15, quad = lane >> 4, ncol = mrow;
  int ksel = quad * 8;
  v4f zero = {0.f, 0.f, 0.f, 0.f};
  double eacc = 0.0;

  for (int mt = w; mt < 13; mt += 4) {
    int m0 = mt * 16;
    v8bf af0 = *(const v8bf*)(Qs + (m0 + mrow) * 72 + ksel);
    v8bf af1 = *(const v8bf*)(Qs + (m0 + mrow) * 72 + 32 + ksel);
    v4f acc[13];
#pragma unroll
    for (int j = 0; j < 13; j++) {
      v8bf bf0 = *(const v8bf*)(Ks + (j * 16 + mrow) * 72 + ksel);
      v8bf bf1 = *(const v8bf*)(Ks + (j * 16 + mrow) * 72 + 32 + ksel);
      v4f t = __builtin_amdgcn_mfma_f32_16x16x32_bf16(af0, bf0, zero, 0, 0, 0);
      acc[j] = __builtin_amdgcn_mfma_f32_16x16x32_bf16(af1, bf1, t, 0, 0, 0);
    }
    float mx[4] = {-1e30f, -1e30f, -1e30f, -1e30f};
#pragma unroll
    for (int j = 0; j < 13; j++) {
      bool colv = (j < 12) || (ncol < 4);
#pragma unroll
      for (int r = 0; r < 4; r++) {
        float sv = colv ? BETA_F * acc[j][r] : -1e30f;
        acc[j][r] = sv;
        mx[r] = fmaxf(mx[r], sv);
      }
    }
#pragma unroll
    for (int o = 1; o < 16; o <<= 1)
#pragma unroll
      for (int r = 0; r < 4; r++) mx[r] = fmaxf(mx[r], __shfl_xor(mx[r], o, 64));
    float zr[4] = {0.f, 0.f, 0.f, 0.f};
#pragma unroll
    for (int j = 0; j < 13; j++)
#pragma unroll
      for (int r = 0; r < 4; r++) {
        float t = (acc[j][r] > -1e29f) ? expf(acc[j][r] - mx[r]) : 0.f;
        acc[j][r] = t;
        zr[r] += t;
      }
#pragma unroll
    for (int o = 1; o < 16; o <<= 1)
#pragma unroll
      for (int r = 0; r < 4; r++) zr[r] += __shfl_xor(zr[r], o, 64);
    if (ncol == 0) {
#pragma unroll
      for (int r = 0; r < 4; r++) {
        int q = m0 + quad * 4 + r;
        if (q < SEQ) eacc += (double)(mx[r] + logf(zr[r]));
      }
    }
    if (SP) {
      float inv[4];
#pragma unroll
      for (int r = 0; r < 4; r++) inv[r] = 1.f / zr[r];
      size_t Pb = Pbase + (size_t)(m0 + quad * 4) * PCOLS;
#pragma unroll
      for (int j = 0; j < 13; j++)
#pragma unroll
        for (int r = 0; r < 4; r++) {
          int q = m0 + quad * 4 + r;
          float pv = (q < SEQ) ? acc[j][r] * inv[r] : 0.f;
          P[Pb + (size_t)r * PCOLS + j * 16 + ncol] = (__bf16)pv;
        }
#pragma unroll
      for (int r = 0; r < 4; r++)
        P[Pb + (size_t)r * PCOLS + 208 + ncol] = (__bf16)0.f;
    }
  }
  for (int o = 32; o; o >>= 1) eacc += __shfl_xor(eacc, o, 64);
  if (lane == 0) er[w] = eacc;
  __syncthreads();
  if (tid == 0)
    *ep_slot = -(double)INV_BETA * ((er[0] + er[1]) + (er[2] + er[3]));
}

// ------------------------------------------------------------------
// MFMA attention backward one side. smem: BT 29696 B.
// z=0: dQ = -(P@K); z=1: dK = -(PT@Q).  A-fragments prefetched.
// ------------------------------------------------------------------
__device__ __forceinline__ void dev_attn_bwd(
    char* smem, const __bf16* __restrict__ Kb, const __bf16* __restrict__ Qb,
    const __bf16* __restrict__ Pg, const __bf16* __restrict__ PTg,
    __bf16* __restrict__ dQg, __bf16* __restrict__ dKg,
    int bh, int z, int tid)
{
  __bf16* BT = (__bf16*)smem;   // 64 x 232
  int b = bh / HN, h = bh - b * HN;
  const __bf16* Bsrc = (z ? Qb : Kb) + (size_t)(b * SEQ) * DIM + h * YD;
  const __bf16* Asrc = (z ? PTg : Pg) + (size_t)bh * PAREA;
  __bf16* Dst = (z ? dKg : dQg) + (size_t)(b * SEQ) * DIM + h * YD;
  for (int i = tid; i < 64 * 232 / 8; i += 256) ((v8bf*)BT)[i] = zero8();
  __syncthreads();
  for (int i = tid; i < SEQ * 8; i += 256) {
    int k = i >> 3, c = i & 7;
    v8bf v = *(const v8bf*)(Bsrc + (size_t)k * DIM + c * 8);
#pragma unroll
    for (int e = 0; e < 8; e++) BT[(c * 8 + e) * 232 + k] = v[e];
  }
  __syncthreads();

  int lane = tid & 63, w = tid >> 6;
  int mrow = lane & 15, quad = lane >> 4, ncol = mrow;
  int ksel = quad * 8;
  for (int mt = w; mt < 13; mt += 4) {
    int m0 = mt * 16;
    v4f acc[4];
    v4f zero = {0.f, 0.f, 0.f, 0.f};
#pragma unroll
    for (int n = 0; n < 4; n++) acc[n] = zero;
    v8bf afc = *(const v8bf*)(Asrc + (size_t)(m0 + mrow) * PCOLS + ksel);
#pragma unroll
    for (int s = 0; s < 7; s++) {
      v8bf afn = (s < 6)
          ? *(const v8bf*)(Asrc + (size_t)(m0 + mrow) * PCOLS + (s + 1) * 32 + ksel)
          : zero8();
#pragma unroll
      for (int n = 0; n < 4; n++) {
        v8bf bf = *(const v8bf*)(BT + (n * 16 + mrow) * 232 + s * 32 + ksel);
        acc[n] = __builtin_amdgcn_mfma_f32_16x16x32_bf16(afc, bf, acc[n], 0, 0, 0);
      }
      afc = afn;
    }
    int row = m0 + quad * 4;
#pragma unroll
    for (int n = 0; n < 4; n++)
#pragma unroll
      for (int r = 0; r < 4; r++)
        if (row + r < SEQ)
          Dst[(size_t)(row + r) * DIM + n * 16 + ncol] = (__bf16)(-acc[n][r]);
  }
}

// ==================================================================
// Dispatch 1: prep = ln_fwd(1568) | cvtall(3456) | cvtT(3456) | init(288)
// ==================================================================
__global__ __launch_bounds__(256) void prep_k(
    const float* __restrict__ x, const float* __restrict__ gamma,
    const float* __restrict__ delta, const float* __restrict__ wk,
    const float* __restrict__ wq, const float* __restrict__ xi,
    __bf16* __restrict__ g, float* __restrict__ xhat, float* __restrict__ rstd,
    __bf16* __restrict__ wk_bf, __bf16* __restrict__ wq_bf,
    __bf16* __restrict__ xi_bf, int* __restrict__ xi8,
    __bf16* __restrict__ wkT, __bf16* __restrict__ wqT, __bf16* __restrict__ xiT,
    __bf16* __restrict__ gt, unsigned char* __restrict__ g8,
    __bf16* __restrict__ dq, __bf16* __restrict__ dk)
{
  __shared__ float s[4];
  __shared__ float tt[32][33];
  int blk = blockIdx.x, tid = threadIdx.x;
  if (blk < 1568) {
    int tok = blk;
    const float* xp = x + (size_t)tok * DIM;
    float v0 = xp[tid], v1 = xp[tid + 256], v2 = xp[tid + 512];
    float sum = v0 + v1 + v2;
    for (int o = 32; o; o >>= 1) sum += __shfl_xor(sum, o, 64);
    if ((tid & 63) == 0) s[tid >> 6] = sum;
    __syncthreads();
    float mu = (s[0] + s[1] + s[2] + s[3]) * (1.0f / DIM);
    __syncthreads();
    float d0 = v0 - mu, d1 = v1 - mu, d2 = v2 - mu;
    float sq = d0 * d0 + d1 * d1 + d2 * d2;
    for (int o = 32; o; o >>= 1) sq += __shfl_xor(sq, o, 64);
    if ((tid & 63) == 0) s[tid >> 6] = sq;
    __syncthreads();
    float var = (s[0] + s[1] + s[2] + s[3]) * (1.0f / DIM);
    float r = rsqrtf(var + LN_EPS_F);
    float xh0 = d0 * r, xh1 = d1 * r, xh2 = d2 * r;
    size_t base = (size_t)tok * DIM;
    g[base + tid]       = (__bf16)(gamma[tid] * xh0 + delta[tid]);
    g[base + tid + 256] = (__bf16)(gamma[tid + 256] * xh1 + delta[tid + 256]);
    g[base + tid + 512] = (__bf16)(gamma[tid + 512] * xh2 + delta[tid + 512]);
    xhat[base + tid] = xh0; xhat[base + tid + 256] = xh1; xhat[base + tid + 512] = xh2;
    if (tid == 0) rstd[tok] = r;
  } else if (blk < 5024) {
    const int W4 = DIM * DIM / 4;
    const int X4 = MXI * DIM / 4;
    int i = (blk - 1568) * 256 + tid;
    if (i < W4) {
      float4 v = ((const float4*)wk)[i];
      v4bf o = { (__bf16)v.x, (__bf16)v.y, (__bf16)v.z, (__bf16)v.w };
      *(v4bf*)(wk_bf + 4 * (size_t)i) = o;
    } else if (i < 2 * W4) {
      int j = i - W4;
      float4 v = ((const float4*)wq)[j];
      v4bf o = { (__bf16)v.x, (__bf16)v.y, (__bf16)v.z, (__bf16)v.w };
      *(v4bf*)(wq_bf + 4 * (size_t)j) = o;
    } else if (i < 2 * W4 + X4) {
      int j = i - 2 * W4;
      float4 v = ((const float4*)xi)[j];
      v4bf o = { (__bf16)v.x, (__bf16)v.y, (__bf16)v.z, (__bf16)v.w };
      *(v4bf*)(xi_bf + 4 * (size_t)j) = o;
      int pk = __builtin_amdgcn_cvt_pk_fp8_f32(16.f * v.x, 16.f * v.y, 0, false);
      pk = __builtin_amdgcn_cvt_pk_fp8_f32(16.f * v.z, 16.f * v.w, pk, true);
      xi8[j] = pk;
    }
  } else if (blk < 8480) {
    int job = blk - 5024;
    const float* src; __bf16* dst; int R; float scale; int r0, c0;
    if (job < 576)       { src = wk; dst = wkT; R = DIM; scale = 1.f;  int j = job;        c0 = (j % 24) * 32; r0 = (j / 24) * 32; }
    else if (job < 1152) { src = wq; dst = wqT; R = DIM; scale = 1.f;  int j = job - 576;  c0 = (j % 24) * 32; r0 = (j / 24) * 32; }
    else                 { src = xi; dst = xiT; R = MXI; scale = -1.f; int j = job - 1152; c0 = (j % 24) * 32; r0 = (j / 24) * 32; }
    int tx = tid & 31, ty = tid >> 5;
    for (int rr = ty; rr < 32; rr += 8)
      tt[rr][tx] = src[(size_t)(r0 + rr) * DIM + c0 + tx];
    __syncthreads();
    for (int rr = ty; rr < 32; rr += 8)
      dst[(size_t)(c0 + rr) * R + r0 + tx] = (__bf16)(scale * tt[tx][rr]);
  } else {
    int i = (blk - 8480) * 256 + tid;
    const int PADN = (MPAD - TOK) * DIM;   // 73728
    if (i < PADN) {
      size_t o = (size_t)TOK * DIM + i;
      g[o] = (__bf16)0.f; dq[o] = (__bf16)0.f; dk[o] = (__bf16)0.f;
#pragma unroll
      for (int t = 0; t < 4; t++) {
        gt[(size_t)t * MPAD * DIM + o] = (__bf16)0.f;
        g8[(size_t)t * MPAD * DIM + o] = 0;
      }
    }
  }
}

// ==================================================================
// Dispatch 2: fwd = fused base attn (96: build K/Q, store Kb/Qb/P,
// energy) | hop base GEMM (312). grid 408.
// ==================================================================
__global__ __launch_bounds__(256, 2) void fwd_k(
    const __bf16* __restrict__ g, const __bf16* __restrict__ wk_bf,
    const __bf16* __restrict__ wq_bf, const __bf16* __restrict__ xi_bf,
    __bf16* __restrict__ Kb, __bf16* __restrict__ Qb, __bf16* __restrict__ P,
    __bf16* __restrict__ rh, double* __restrict__ ep)
{
  __shared__ __align__(16) char smem[SM_ATTN];
  int blk = blockIdx.x, tid = threadIdx.x;
  if (blk < 96) {
    int bh = blk, b = bh / HN, h = bh - b * HN;
    const __bf16* gsrc = g + (size_t)(b * SEQ) * DIM;
    dev_build_attn_kq(smem, gsrc, wk_bf + (size_t)h * YD * DIM,
                      wq_bf + (size_t)h * YD * DIM, tid);
    dev_store_kq(smem, Kb + (size_t)(b * SEQ) * DIM + h * YD,
                 Qb + (size_t)(b * SEQ) * DIM + h * YD, tid);
    dev_attn_core<1>(smem, P, (size_t)bh * PAREA, ep + bh, tid);
  } else {
    int j = blk - 96;
    int ry = j / 24, nx = j - ry * 24;
    v4f acc[4][4];
    acc_zero(acc);
    gemm_core_bf16(smem, g, DIM, xi_bf, DIM, ry * 128, nx * 128, 0, 24, acc, tid);
    epi_relu_energy(acc, rh, MXI, ry * 128, nx * 128, tid,
                    (double*)(smem + OFF_ER), ep + EP_HOPB + ry * 24 + nx);
  }
}

// ==================================================================
// Dispatch 3: P -> PT transpose. grid (96, 7, 7).
// ==================================================================
__global__ __launch_bounds__(256) void ptrans_k(
    const __bf16* __restrict__ Pg, __bf16* __restrict__ PTg)
{
  __shared__ __bf16 t[32][33];
  int bh = blockIdx.x;
  int q0 = blockIdx.y * 32, k0 = blockIdx.z * 32;
  int tx = threadIdx.x & 31, ty = threadIdx.x >> 5;
  const __bf16* Pb = Pg + (size_t)bh * PAREA;
  __bf16* PTb = PTg + (size_t)bh * PAREA;
  for (int rr = ty; rr < 32; rr += 8)
    t[rr][tx] = (q0 + rr < PROWS) ? Pb[(size_t)(q0 + rr) * PCOLS + k0 + tx] : (__bf16)0.f;
  __syncthreads();
  for (int rr = ty; rr < 32; rr += 8)
    if (k0 + rr < PROWS)
      PTb[(size_t)(k0 + rr) * PCOLS + q0 + tx] = t[tx][rr];
}

// ==================================================================
// Dispatch 4: bwdA = attn_bwd z0 (96) | z1 (96) | rh@xiT quarters (312).
// grid 504.
// ==================================================================
__global__ __launch_bounds__(256, 4) void bwdA_k(
    const __bf16* __restrict__ Kb, const __bf16* __restrict__ Qb,
    const __bf16* __restrict__ P, const __bf16* __restrict__ PT,
    __bf16* __restrict__ dQg, __bf16* __restrict__ dKg,
    const __bf16* __restrict__ rh, const __bf16* __restrict__ xiT,
    float* __restrict__ dGp)
{
  __shared__ __align__(16) char smem[32768];
  int blk = blockIdx.x, tid = threadIdx.x;
  if (blk < 192) {
    int z = blk / 96, bh = blk - z * 96;
    dev_attn_bwd(smem, Kb, Qb, P, PT, dQg, dKg, bh, z, tid);
  } else {
    int j = blk - 192;          // 0..311
    int qd = j / 78, jj = j - qd * 78;
    int my = jj / 6, nx = jj - my * 6;
    v4f acc[4][4];
    acc_zero(acc);
    gemm_core_bf16(smem, rh, MXI, xiT, MXI, my * 128, nx * 128, qd * 768, 24, acc, tid);
    epi_store_f32(acc, dGp + (size_t)qd * NPE, my * 128, nx * 128, tid);
  }
}

// ==================================================================
// Dispatch 5: bwdB = dQg@wqT halves | dKg@wkT halves. grid 312.
// ==================================================================
__global__ __launch_bounds__(256, 4) void bwdB_k(
    const __bf16* __restrict__ dQg, const __bf16* __restrict__ wqT,
    const __bf16* __restrict__ dKg, const __bf16* __restrict__ wkT,
    float* __restrict__ dGp)
{
  __shared__ __align__(16) char smem[32768];
  int blk = blockIdx.x, tid = threadIdx.x;
  int z = blk / 156, jj = blk - z * 156;
  int half = jj / 78, j2 = jj - half * 78;
  int my = j2 / 6, nx = j2 - my * 6;
  const __bf16* A = z ? dKg : dQg;
  const __bf16* B = z ? wkT : wqT;
  v4f acc[4][4];
  acc_zero(acc);
  gemm_core_bf16(smem, A, DIM, B, DIM, my * 128, nx * 128, half * 384, 12, acc, tid);
  epi_store_f32(acc, dGp + (size_t)(4 + z * 2 + half) * NPE, my * 128, nx * 128, tid);
}

// ==================================================================
// Dispatch 6: fused LN-backward (sum 8 partials) + trial axpy+LN. grid 1568.
// ==================================================================
__global__ __launch_bounds__(256) void lnbwd_axpy_k(
    const float* __restrict__ dGp,
    const float* __restrict__ xhat, const float* __restrict__ rstd,
    const float* __restrict__ gamma, const float* __restrict__ delta,
    const float* __restrict__ x, float* __restrict__ grad,
    __bf16* __restrict__ gt, unsigned char* __restrict__ g8)
{
  __shared__ float s[8];
  int tok = blockIdx.x, tid = threadIdx.x;
  size_t base = (size_t)tok * DIM;
  float ga0 = gamma[tid], ga1 = gamma[tid + 256], ga2 = gamma[tid + 512];
  float de0 = delta[tid], de1 = delta[tid + 256], de2 = delta[tid + 512];
  float g0 = 0.f, g1 = 0.f, g2 = 0.f;
#pragma unroll
  for (int pi = 0; pi < 8; pi++) {
    const float* p = dGp + (size_t)pi * NPE;
    g0 += p[base + tid];
    g1 += p[base + tid + 256];
    g2 += p[base + tid + 512];
  }
  float dh0 = g0 * ga0, dh1 = g1 * ga1, dh2 = g2 * ga2;
  float xh0 = xhat[base + tid], xh1 = xhat[base + tid + 256], xh2 = xhat[base + tid + 512];
  float s1 = dh0 + dh1 + dh2;
  float s2 = dh0 * xh0 + dh1 * xh1 + dh2 * xh2;
  for (int o = 32; o; o >>= 1) { s1 += __shfl_xor(s1, o, 64); s2 += __shfl_xor(s2, o, 64); }
  if ((tid & 63) == 0) { s[tid >> 6] = s1; s[4 + (tid >> 6)] = s2; }
  __syncthreads();
  float m1 = (s[0] + s[1] + s[2] + s[3]) * (1.0f / DIM);
  float m2 = (s[4] + s[5] + s[6] + s[7]) * (1.0f / DIM);
  float r = rstd[tok];
  float gr0 = r * (dh0 - m1 - xh0 * m2);
  float gr1 = r * (dh1 - m1 - xh1 * m2);
  float gr2 = r * (dh2 - m1 - xh2 * m2);
  grad[base + tid] = gr0; grad[base + tid + 256] = gr1; grad[base + tid + 512] = gr2;
  float xv0 = x[base + tid], xv1 = x[base + tid + 256], xv2 = x[base + tid + 512];
#pragma unroll
  for (int t = 0; t < 4; t++) {
    float lr = 1.0f / (float)(1 << t);
    float v0 = xv0 - lr * gr0, v1 = xv1 - lr * gr1, v2 = xv2 - lr * gr2;
    float sum = v0 + v1 + v2;
    for (int o = 32; o; o >>= 1) sum += __shfl_xor(sum, o, 64);
    __syncthreads();
    if ((tid & 63) == 0) s[tid >> 6] = sum;
    __syncthreads();
    float mu = (s[0] + s[1] + s[2] + s[3]) * (1.0f / DIM);
    float d0 = v0 - mu, d1 = v1 - mu, d2 = v2 - mu;
    float sq = d0 * d0 + d1 * d1 + d2 * d2;
    for (int o = 32; o; o >>= 1) sq += __shfl_xor(sq, o, 64);
    __syncthreads();
    if ((tid & 63) == 0) s[tid >> 6] = sq;
    __syncthreads();
    float var = (s[0] + s[1] + s[2] + s[3]) * (1.0f / DIM);
    float r2 = rsqrtf(var + LN_EPS_F);
    float o0 = ga0 * (d0 * r2) + de0;
    float o1 = ga1 * (d1 * r2) + de1;
    float o2 = ga2 * (d2 * r2) + de2;
    size_t ob = ((size_t)t * MPAD + tok) * DIM;
    gt[ob + tid] = (__bf16)o0; gt[ob + tid + 256] = (__bf16)o1; gt[ob + tid + 512] = (__bf16)o2;
    g8[ob + tid]       = (unsigned char)(__builtin_amdgcn_cvt_pk_fp8_f32(o0, o0, 0, false) & 0xff);
    g8[ob + tid + 256] = (unsigned char)(__builtin_amdgcn_cvt_pk_fp8_f32(o1, o1, 0, false) & 0xff);
    g8[ob + tid + 512] = (unsigned char)(__builtin_amdgcn_cvt_pk_fp8_f32(o2, o2, 0, false) & 0xff);
  }
}

// ==================================================================
// Dispatch 7: fp8 trial hopfield, 624 blocks x 2 jobs, XCD-swizzled:
// xcd = id&7 owns nx in {3*xcd .. 3*xcd+2} -> xi8 not replicated per XCD.
// ==================================================================
__global__ __launch_bounds__(256, 4) void hop8_k(
    const unsigned char* __restrict__ g8, const unsigned char* __restrict__ xi8,
    double* __restrict__ ep)
{
  __shared__ __align__(16) char smem[16416];
  int tid = threadIdx.x;
#pragma unroll
  for (int jj = 0; jj < 2; jj++) {
    int id = blockIdx.x + jj * 624;
    __syncthreads();
    int xcd = id & 7, q = id >> 3;        // q: 0..155
    int nx = xcd * 3 + q % 3;             // 0..23
    int my = q / 3;                       // 0..51
    dev_gemm_fp8(smem, g8, xi8, ep, my, nx, tid);
  }
}

// ==================================================================
// Dispatch 8: fused trial attention, 1D grid 384, XCD-swizzled:
// xcd = id&7 owns 4 (b,t) g-slabs -> g_tr not replicated per XCD.
// ==================================================================
__global__ __launch_bounds__(256, 2) void tattn_k(
    const __bf16* __restrict__ gt, const __bf16* __restrict__ wk_bf,
    const __bf16* __restrict__ wq_bf, double* __restrict__ ep)
{
  __shared__ __align__(16) char smem[SM_ATTN];
  int id = blockIdx.x, tid = threadIdx.x;
  int xcd = id & 7, q = id >> 3;          // q: 0..47
  int bt = xcd * 4 + (q & 3);             // 0..31
  int h = q >> 2;                         // 0..11
  int b = bt >> 2, t = bt & 3;
  int bh = b * HN + h;
  const __bf16* gsrc = gt + ((size_t)t * MPAD + b * SEQ) * DIM;
  dev_build_attn_kq(smem, gsrc, wk_bf + (size_t)h * YD * DIM,
                    wq_bf + (size_t)h * YD * DIM, tid);
  dev_attn_core<0>(smem, (__bf16*)nullptr, 0, ep + (t + 1) * 96 + bh, tid);
}

// ==================================================================
// Dispatch 9: fused reduce+choose+update. grid 624 (grid-stride).
// ==================================================================
__global__ __launch_bounds__(256) void update_k(
    const float* __restrict__ x, const float* __restrict__ grad,
    const double* __restrict__ ep, float* __restrict__ out, int n4)
{
  __shared__ double sm[4];
  __shared__ float chs;
  int tid = threadIdx.x;
  double e[5];
  for (int s = 0; s < 5; s++) {
    double acc = 0.0;
    int a0 = 96 * s;
    for (int i = tid; i < 96; i += 256) acc += ep[a0 + i];
    int b0 = (s == 0) ? EP_HOPB : EP_HOPT + 312 * (s - 1);
    for (int i = tid; i < 312; i += 256) acc += ep[b0 + i];
    for (int o = 32; o; o >>= 1) acc += __shfl_xor(acc, o, 64);
    if ((tid & 63) == 0) sm[tid >> 6] = acc;
    __syncthreads();
    e[s] = (sm[0] + sm[1]) + (sm[2] + sm[3]);
    __syncthreads();
  }
  if (tid == 0) {
    double e0 = e[0];
    float c = 0.0625f;
    if (e[4] < e0) c = 0.125f;
    if (e[3] < e0) c = 0.25f;
    if (e[2] < e0) c = 0.5f;
    if (e[1] < e0) c = 1.0f;
    chs = c;
  }
  __syncthreads();
  float lr = chs;
  for (int i = blockIdx.x * 256 + tid; i < n4; i += gridDim.x * 256) {
    const float4 xv = ((const float4*)x)[i];
    const float4 gv = ((const float4*)grad)[i];
    float4 o;
    o.x = xv.x - lr * gv.x; o.y = xv.y - lr * gv.y;
    o.z = xv.z - lr * gv.z; o.w = xv.w - lr * gv.w;
    ((float4*)out)[i] = o;
  }
}

// ------------------------------------------------------------------
extern "C" void kernel_launch(void* const* d_in, const int* in_sizes, int n_in,
                              void* d_out, int out_size, void* d_ws, size_t ws_size,
                              hipStream_t stream)
{
  const float* x     = (const float*)d_in[0];
  const float* gamma = (const float*)d_in[1];
  const float* delta = (const float*)d_in[2];
  const float* wk    = (const float*)d_in[3];
  const float* wq    = (const float*)d_in[4];
  const float* xi    = (const float*)d_in[5];
  float* out = (float*)d_out;

  const size_t NE = (size_t)TOK * DIM;
  const size_t NP = NPE;

  double* eparts = (double*)d_ws;                // 2040 doubles
  float* fp = (float*)(eparts + EP_TOTAL + 8);
  float* xhat = fp;  fp += NE;
  float* grad = fp;  fp += NE;
  float* rstd = fp;  fp += TOK;
  fp += 16;
  float* dGp = (float*)(((uintptr_t)fp + 15) & ~(uintptr_t)15);   // 8 * NP floats
  __bf16* bp = (__bf16*)(dGp + 8 * NP);
  __bf16* g_bf   = bp;  bp += NP;
  __bf16* g_tr   = bp;  bp += 4 * NP;
  __bf16* Kb_bf  = bp;  bp += NP;
  __bf16* Qb_bf  = bp;  bp += NP;
  __bf16* dQg_bf = bp;  bp += NP;
  __bf16* dKg_bf = bp;  bp += NP;
  __bf16* rh_bf  = bp;  bp += (size_t)MPAD * MXI;
  __bf16* wk_bf  = bp;  bp += (size_t)DIM * DIM;
  __bf16* wq_bf  = bp;  bp += (size_t)DIM * DIM;
  __bf16* wkT_bf = bp;  bp += (size_t)DIM * DIM;
  __bf16* wqT_bf = bp;  bp += (size_t)DIM * DIM;
  __bf16* xi_bf  = bp;  bp += (size_t)MXI * DIM;
  __bf16* xiT_bf = bp;  bp += (size_t)DIM * MXI;
  __bf16* P_bf   = bp;  bp += (size_t)96 * PAREA;
  __bf16* PT_bf  = bp;  bp += (size_t)96 * PAREA;
  unsigned char* g8  = (unsigned char*)bp;  bp += 2 * NP;              // 4*NP bytes
  unsigned char* xi8 = (unsigned char*)bp;  bp += (size_t)MXI * DIM / 2;

  const int n4 = (int)(NE / 4);
  dim3 blk(256);

  // 1. prep
  hipLaunchKernelGGL(prep_k, dim3(8768), blk, 0, stream,
                     x, gamma, delta, wk, wq, xi,
                     g_bf, xhat, rstd, wk_bf, wq_bf, xi_bf, (int*)xi8,
                     wkT_bf, wqT_bf, xiT_bf, g_tr, g8, dQg_bf, dKg_bf);
  // 2. fused base attn + hop base
  hipLaunchKernelGGL(fwd_k, dim3(408), blk, 0, stream,
                     g_bf, wk_bf, wq_bf, xi_bf, Kb_bf, Qb_bf, P_bf, rh_bf, eparts);
  // 3. ptrans
  hipLaunchKernelGGL(ptrans_k, dim3(96, 7, 7), blk, 0, stream, P_bf, PT_bf);
  // 4. attn_bwd + rh@xiT quarters
  hipLaunchKernelGGL(bwdA_k, dim3(504), blk, 0, stream,
                     Kb_bf, Qb_bf, P_bf, PT_bf, dQg_bf, dKg_bf, rh_bf, xiT_bf, dGp);
  // 5. dQg@wqT + dKg@wkT (K-halved)
  hipLaunchKernelGGL(bwdB_k, dim3(312), blk, 0, stream,
                     dQg_bf, wqT_bf, dKg_bf, wkT_bf, dGp);
  // 6. ln_bwd + trial axpy/LN fused
  hipLaunchKernelGGL(lnbwd_axpy_k, dim3(TOK), blk, 0, stream,
                     dGp, xhat, rstd, gamma, delta, x, grad, g_tr, g8);
  // 7. fp8 trial hopfield (XCD-swizzled)
  hipLaunchKernelGGL(hop8_k, dim3(624), blk, 0, stream, g8, xi8, eparts);
  // 8. fused trial attention (XCD-swizzled)
  hipLaunchKernelGGL(tattn_k, dim3(384), blk, 0, stream,
                     g_tr, wk_bf, wq_bf, eparts);
  // 9. reduce + choose + update
  hipLaunchKernelGGL(update_k, dim3(624), blk, 0, stream,
                     x, grad, eparts, out, n4);
}